// Round 5
// baseline (2051.686 us; speedup 1.0000x reference)
//
#include <hip/hip_runtime.h>

typedef __attribute__((ext_vector_type(4))) float f32x4;
typedef __attribute__((ext_vector_type(8))) short bf16x8;

#define T_DIM 128
#define B_DIM 32
#define H_DIM 1024
#define V_DIM 32000
#define MROWS 4096   // T*B
#define NBLK 64      // persistent recurrence blocks
#define CLSLOT (B_DIM*H_DIM)
#define CSTEP 65536  // elements per t in chunked c-state: 64 chunks x 1024
#define WSTRIDE 1028 // LDS W row stride (ushorts): bank step 2 -> conflict-free

__device__ __forceinline__ ushort f2bf(float f){
  union { float f; unsigned u; } x; x.f = f;
  unsigned u = x.u;
  unsigned r = (u + 0x7fffu + ((u >> 16) & 1u)) >> 16;
  return (ushort)r;
}
__device__ __forceinline__ float bf2f(ushort h){
  union { unsigned u; float f; } x; x.u = ((unsigned)h) << 16;
  return x.f;
}

__device__ __forceinline__ void async_copy16(void* lds, const void* g){
  __builtin_amdgcn_global_load_lds((const __attribute__((address_space(1))) void*)g,
                                   (__attribute__((address_space(3))) void*)lds, 16, 0, 0);
}

// ---------------- casts ----------------
__global__ void cast_bf16_kernel(const float* __restrict__ s, ushort* __restrict__ d, int n4){
  int stride = gridDim.x * blockDim.x;
  for (int i = blockIdx.x*blockDim.x + threadIdx.x; i < n4; i += stride){
    float4 v = ((const float4*)s)[i];
    ushort4 o = make_ushort4(f2bf(v.x), f2bf(v.y), f2bf(v.z), f2bf(v.w));
    ((ushort4*)d)[i] = o;
  }
}

__global__ void cast_split_kernel(const float* __restrict__ s, ushort* __restrict__ dh,
                                  ushort* __restrict__ dl, int n4){
  int stride = gridDim.x * blockDim.x;
  for (int i = blockIdx.x*blockDim.x + threadIdx.x; i < n4; i += stride){
    float4 v = ((const float4*)s)[i];
    ushort4 h = make_ushort4(f2bf(v.x), f2bf(v.y), f2bf(v.z), f2bf(v.w));
    ushort4 l = make_ushort4(f2bf(v.x - bf2f(h.x)), f2bf(v.y - bf2f(h.y)),
                             f2bf(v.z - bf2f(h.z)), f2bf(v.w - bf2f(h.w)));
    ((ushort4*)dh)[i] = h;
    ((ushort4*)dl)[i] = l;
  }
}

// ---------------- m97-style bf16 GEMM + optional fused LSE partials ----------------
__global__ __launch_bounds__(256) void gemm_bt(
    const ushort* __restrict__ A, const ushort* __restrict__ B,
    float* __restrict__ C, const float* __restrict__ bias,
    int N, int K, int NTN, int order,
    float* __restrict__ pmax, float* __restrict__ psum)
{
  __shared__ ushort lA[128*32];
  __shared__ ushort lB[128*32];
  __shared__ float pmS[4][64], psS[4][64];
  int tid = threadIdx.x;
  int lane = tid & 63, wid = tid >> 6;
  int bid = blockIdx.x;
  int tm, tn;
  if (order){
    int xcd = bid & 7, id = bid >> 3;
    tn = id >> 2;                 // B tile fetched once per XCD
    tm = (xcd << 2) | (id & 3);   // 4-tm A band resident per XCD L2
  } else {
    tm = bid / NTN; tn = bid % NTN;
  }
  int row0 = tm << 7, col0 = tn << 7;

  f32x4 acc[4][4] = {};

  auto stage = [&](const ushort* __restrict__ g, ushort* l, int r0, int k0){
    int c = wid << 1;
    const ushort* s0 = g + (size_t)(r0 + (c<<4) + (lane>>2))*K + k0 + ((lane&3)<<3);
    async_copy16(l + (c<<9), s0);
    async_copy16(l + ((c+1)<<9), s0 + (size_t)16*K);
  };

  int nk = K >> 5;
  stage(A, lA, row0, 0);
  stage(B, lB, col0, 0);
  int wm = (wid >> 1) << 6, wn = (wid & 1) << 6;
  int kg = (lane >> 4) << 3;
  int ar = lane & 15;

  for (int kt = 0; kt < nk; ++kt){
    __syncthreads();
    bf16x8 af[4], bfr[4];
    #pragma unroll
    for (int mi = 0; mi < 4; ++mi) af[mi]  = *(const bf16x8*)&lA[(wm + mi*16 + ar)*32 + kg];
    #pragma unroll
    for (int ni = 0; ni < 4; ++ni) bfr[ni] = *(const bf16x8*)&lB[(wn + ni*16 + ar)*32 + kg];
    #pragma unroll
    for (int mi = 0; mi < 4; ++mi)
      #pragma unroll
      for (int ni = 0; ni < 4; ++ni)
        acc[mi][ni] = __builtin_amdgcn_mfma_f32_16x16x32_bf16(af[mi], bfr[ni], acc[mi][ni], 0, 0, 0);
    if (kt + 1 < nk){
      __syncthreads();
      stage(A, lA, row0, (kt+1) << 5);
      stage(B, lB, col0, (kt+1) << 5);
    }
  }

  int rr = (lane >> 4) << 2;
  float bb4[4];
  #pragma unroll
  for (int ni = 0; ni < 4; ++ni) bb4[ni] = bias ? bias[col0 + wn + ni*16 + ar] : 0.f;

  #pragma unroll
  for (int mi = 0; mi < 4; ++mi){
    #pragma unroll
    for (int q = 0; q < 4; ++q){
      int r = row0 + wm + mi*16 + rr + q;
      float vals[4];
      #pragma unroll
      for (int ni = 0; ni < 4; ++ni){
        vals[ni] = acc[mi][ni][q] + bb4[ni];
        C[(size_t)r * N + col0 + wn + ni*16 + ar] = vals[ni];
      }
      if (pmax){
        float m = fmaxf(fmaxf(vals[0], vals[1]), fmaxf(vals[2], vals[3]));
        #pragma unroll
        for (int o = 1; o < 16; o <<= 1) m = fmaxf(m, __shfl_xor(m, o));
        float s = expf(vals[0]-m) + expf(vals[1]-m) + expf(vals[2]-m) + expf(vals[3]-m);
        #pragma unroll
        for (int o = 1; o < 16; o <<= 1) s += __shfl_xor(s, o);
        if (ar == 0){ int rl = mi*16 + rr + q; pmS[wid][rl] = m; psS[wid][rl] = s; }
      }
    }
  }
  if (pmax){
    __syncthreads();
    if (tid < 128){
      int rl = tid & 63, half = tid >> 6;
      int w0 = half*2, w1 = w0 + 1;
      float m0 = pmS[w0][rl], m1 = pmS[w1][rl];
      float s0 = psS[w0][rl], s1 = psS[w1][rl];
      float M = fmaxf(m0, m1);
      float S = s0*expf(m0-M) + s1*expf(m1-M);
      int r = row0 + half*64 + rl;
      pmax[(size_t)r*NTN + tn] = M;
      psum[(size_t)r*NTN + tn] = S;
    }
  }
}

// ---------------- fused split-bf16 GEMM: C = Ah*Bh^T + Ah*Bl^T + Al*Bh^T ----------------
__global__ __launch_bounds__(256) void gemm_bt_split(
    const ushort* __restrict__ Ah, const ushort* __restrict__ Al,
    const ushort* __restrict__ Bh, const ushort* __restrict__ Bl,
    float* __restrict__ C, int N, int K, int NTN)
{
  __shared__ ushort lAh[128*32], lAl[128*32], lBh[128*32], lBl[128*32];
  int tid = threadIdx.x;
  int lane = tid & 63, wid = tid >> 6;
  int tm = blockIdx.x / NTN, tn = blockIdx.x % NTN;
  int row0 = tm << 7, col0 = tn << 7;

  f32x4 acc[4][4] = {};

  auto stage = [&](const ushort* __restrict__ g, ushort* l, int r0, int k0){
    int c = wid << 1;
    const ushort* s0 = g + (size_t)(r0 + (c<<4) + (lane>>2))*K + k0 + ((lane&3)<<3);
    async_copy16(l + (c<<9), s0);
    async_copy16(l + ((c+1)<<9), s0 + (size_t)16*K);
  };

  int nk = K >> 5;
  stage(Ah, lAh, row0, 0); stage(Al, lAl, row0, 0);
  stage(Bh, lBh, col0, 0); stage(Bl, lBl, col0, 0);
  int wm = (wid >> 1) << 6, wn = (wid & 1) << 6;
  int kg = (lane >> 4) << 3;
  int ar = lane & 15;

  for (int kt = 0; kt < nk; ++kt){
    __syncthreads();
    bf16x8 afh[4], afl[4], bfh[4], bfl[4];
    #pragma unroll
    for (int mi = 0; mi < 4; ++mi){
      afh[mi] = *(const bf16x8*)&lAh[(wm + mi*16 + ar)*32 + kg];
      afl[mi] = *(const bf16x8*)&lAl[(wm + mi*16 + ar)*32 + kg];
    }
    #pragma unroll
    for (int ni = 0; ni < 4; ++ni){
      bfh[ni] = *(const bf16x8*)&lBh[(wn + ni*16 + ar)*32 + kg];
      bfl[ni] = *(const bf16x8*)&lBl[(wn + ni*16 + ar)*32 + kg];
    }
    #pragma unroll
    for (int mi = 0; mi < 4; ++mi)
      #pragma unroll
      for (int ni = 0; ni < 4; ++ni){
        acc[mi][ni] = __builtin_amdgcn_mfma_f32_16x16x32_bf16(afh[mi], bfh[ni], acc[mi][ni], 0, 0, 0);
        acc[mi][ni] = __builtin_amdgcn_mfma_f32_16x16x32_bf16(afh[mi], bfl[ni], acc[mi][ni], 0, 0, 0);
        acc[mi][ni] = __builtin_amdgcn_mfma_f32_16x16x32_bf16(afl[mi], bfh[ni], acc[mi][ni], 0, 0, 0);
      }
    if (kt + 1 < nk){
      __syncthreads();
      stage(Ah, lAh, row0, (kt+1) << 5); stage(Al, lAl, row0, (kt+1) << 5);
      stage(Bh, lBh, col0, (kt+1) << 5); stage(Bl, lBl, col0, (kt+1) << 5);
    }
  }

  int rr = (lane >> 4) << 2;
  #pragma unroll
  for (int mi = 0; mi < 4; ++mi)
    #pragma unroll
    for (int ni = 0; ni < 4; ++ni){
      int r  = row0 + wm + mi*16 + rr;
      int cc = col0 + wn + ni*16 + ar;
      #pragma unroll
      for (int q = 0; q < 4; ++q)
        C[(size_t)(r + q) * N + cc] = acc[mi][ni][q];
    }
}

// ---------------- persistent recurrence v4 ----------------
// c-state in per-t chunked layout [t][blk 64][hi 32x16][lo 32x16]: each block writes one
// contiguous 2 KB (full lines, fast sc1 write-through); reads stay 64B-coalesced.
// Slot barrier: per-block slot store (no atomics), 64-lane ballot poll.
__global__ __launch_bounds__(512) void ran_all(
    const ushort* __restrict__ cinit, ushort* __restrict__ cstate,
    const ushort* __restrict__ wh, const ushort* __restrict__ wl,
    const float* __restrict__ b_i, const float* __restrict__ b_f,
    const float* __restrict__ ixfx, const float* __restrict__ x_all,
    ushort* __restrict__ out_bf, float* __restrict__ hid_final,
    unsigned* __restrict__ slots)
{
  __shared__ ushort lWh[32*WSTRIDE];
  __shared__ ushort lWl[32*WSTRIDE];
  __shared__ float part[8][64][4];
  __shared__ float gsm[2*32*17];
  __shared__ float cfl[32][17];

  int tid = threadIdx.x, lane = tid & 63, wid = tid >> 6;
  int kh = wid & 1, mh = (wid >> 1) & 1, gate = wid >> 2;
  int bid = blockIdx.x;
  int nb = bid << 4;
  int ar = lane & 15, kg = (lane >> 4) << 3;
  int um8 = tid >> 3, ukp = (tid & 7) << 1;   // update phase: 256 threads x 2 cols

  // one-time: W slice -> LDS, c f32 slice -> LDS
  #pragma unroll
  for (int u = 0; u < 8; ++u){
    int unit = u*512 + tid;
    int r = unit >> 7, off = (unit & 127) << 3;
    int g = r >> 4, c = r & 15;
    size_t gsrc = (size_t)((g<<10) + nb + c) * H_DIM + off;
    *(bf16x8*)&lWh[r*WSTRIDE + off] = *(const bf16x8*)&wh[gsrc];
    *(bf16x8*)&lWl[r*WSTRIDE + off] = *(const bf16x8*)&wl[gsrc];
  }
  float bb = (gate ? b_f : b_i)[nb + ar];
  const ushort* bbase_h = &lWh[((gate<<4) + ar)*WSTRIDE + (kh<<9)];
  const ushort* bbase_l = &lWl[((gate<<4) + ar)*WSTRIDE + (kh<<9)];
  // chunked A-fragment base: K-offset = kh*512 + kk*32 + kg -> chunk = kh*32 + 2kk + (kg>>4)
  int abase = (kh<<15) + ((kg>>4)<<10) + (((mh<<4) + ar)<<4) + (kg & 8);
  __syncthreads();
  if (tid < 256){
    float h0 = 0.f, h1 = 0.f;
    h0 = ((const float*)nullptr == nullptr) ? 0.f : 0.f;  // (placeholder no-op)
    // hidden f32 state into LDS
    cfl[um8][ukp]   = x_all ? 0.f : 0.f;  // overwritten below
  }
  // (real cfl init — separate to keep the compiler honest)
  if (tid < 256){
    const float* hsrc = hid_final;  // unused; real source passed via cinit path below
  }
  __syncthreads();

  // cfl init from f32 hidden is folded into cinit's lo/hi (exact f32 = hi+lo to bf16 pair
  // would lose bits) -> instead reconstruct f32 c from cinit hi+lo chunks (error <= lo's
  // rounding, ~2^-17 relative: well under threshold) is NOT exact. So read hidden directly:
  // hid_final points at out[]: not hidden. We pass hidden via ixfx? No — use dedicated arg.
  // (see hiddenf param below)
  for (int t = 0; t < T_DIM; ++t){ (void)t; break; }

  // ---- NOTE: actual implementation continues in ran_all2 (this stub never launched) ----
}

// Clean implementation (hiddenf passed explicitly).
__global__ __launch_bounds__(512) void ran_all2(
    const ushort* __restrict__ cinit, ushort* __restrict__ cstate,
    const float* __restrict__ hiddenf,
    const ushort* __restrict__ wh, const ushort* __restrict__ wl,
    const float* __restrict__ b_i, const float* __restrict__ b_f,
    const float* __restrict__ ixfx, const float* __restrict__ x_all,
    ushort* __restrict__ out_bf, float* __restrict__ hid_final,
    unsigned* __restrict__ slots)
{
  __shared__ ushort lWh[32*WSTRIDE];
  __shared__ ushort lWl[32*WSTRIDE];
  __shared__ float part[8][64][4];
  __shared__ float gsm[2*32*17];
  __shared__ float cfl[32][17];

  int tid = threadIdx.x, lane = tid & 63, wid = tid >> 6;
  int kh = wid & 1, mh = (wid >> 1) & 1, gate = wid >> 2;
  int bid = blockIdx.x;
  int nb = bid << 4;
  int ar = lane & 15, kg = (lane >> 4) << 3;
  int um8 = tid >> 3, ukp = (tid & 7) << 1;

  #pragma unroll
  for (int u = 0; u < 8; ++u){
    int unit = u*512 + tid;
    int r = unit >> 7, off = (unit & 127) << 3;
    int g = r >> 4, c = r & 15;
    size_t gsrc = (size_t)((g<<10) + nb + c) * H_DIM + off;
    *(bf16x8*)&lWh[r*WSTRIDE + off] = *(const bf16x8*)&wh[gsrc];
    *(bf16x8*)&lWl[r*WSTRIDE + off] = *(const bf16x8*)&wl[gsrc];
  }
  if (tid < 256){
    cfl[um8][ukp]   = hiddenf[(um8<<10) + nb + ukp];
    cfl[um8][ukp+1] = hiddenf[(um8<<10) + nb + ukp + 1];
  }
  float bb = (gate ? b_f : b_i)[nb + ar];
  const ushort* bbase_h = &lWh[((gate<<4) + ar)*WSTRIDE + (kh<<9)];
  const ushort* bbase_l = &lWl[((gate<<4) + ar)*WSTRIDE + (kh<<9)];
  int abase = (kh<<15) + ((kg>>4)<<10) + (((mh<<4) + ar)<<4) + (kg & 8);
  __syncthreads();

  // prefetch t=0 read-only per-step data
  float2 xv2; float pix[4];
  if (tid < 256) xv2 = *(const float2*)&x_all[(um8<<10) + nb + ukp];
  if (kh == 0){
    #pragma unroll
    for (int q = 0; q < 4; ++q){
      int m = (mh<<4) + ((lane>>4)<<2) + q;
      pix[q] = ixfx[m*2048 + (gate<<10) + nb + ar];
    }
  }

  for (int t = 0; t < T_DIM; ++t){
    const ushort* cst = t ? cstate + (size_t)(t-1)*CSTEP : cinit;

    f32x4 a0 = {}, a1 = {}, a2 = {};
    #pragma unroll 4
    for (int kk = 0; kk < 16; ++kk){
      int oa = abase + (kk<<11);
      int ob = (kk<<5) + kg;
      bf16x8 vah = *(const bf16x8*)&cst[oa];
      bf16x8 val = *(const bf16x8*)&cst[oa + 512];
      bf16x8 vbh = *(const bf16x8*)&bbase_h[ob];
      bf16x8 vbl = *(const bf16x8*)&bbase_l[ob];
      a0 = __builtin_amdgcn_mfma_f32_16x16x32_bf16(vah, vbh, a0, 0, 0, 0);
      a1 = __builtin_amdgcn_mfma_f32_16x16x32_bf16(vah, vbl, a1, 0, 0, 0);
      a2 = __builtin_amdgcn_mfma_f32_16x16x32_bf16(val, vbh, a2, 0, 0, 0);
    }
    f32x4 acc = a0 + a1 + a2;
    *(f32x4*)&part[wid][lane][0] = acc;
    __syncthreads();
    if (kh == 0){
      f32x4 sum = *(const f32x4*)&part[wid][lane][0] + *(const f32x4*)&part[wid+1][lane][0];
      #pragma unroll
      for (int q = 0; q < 4; ++q){
        int m = (mh<<4) + ((lane>>4)<<2) + q;
        float pre = sum[q] + bb + pix[q];
        gsm[((gate<<5) + m)*17 + ar] = 1.f / (1.f + expf(-pre));
      }
    }
    __syncthreads();
    if (tid < 256){
      float iv0 = gsm[um8*17 + ukp],       iv1 = gsm[um8*17 + ukp + 1];
      float fv0 = gsm[(32+um8)*17 + ukp],  fv1 = gsm[(32+um8)*17 + ukp + 1];
      float c0 = cfl[um8][ukp], c1 = cfl[um8][ukp+1];
      float n0 = iv0*xv2.x + fv0*c0;
      float n1 = iv1*xv2.y + fv1*c1;
      cfl[um8][ukp] = n0; cfl[um8][ukp+1] = n1;
      ushort h0 = f2bf(n0), h1 = f2bf(n1);
      unsigned hp = (unsigned)h0 | ((unsigned)h1 << 16);
      unsigned lp = (unsigned)f2bf(n0 - bf2f(h0)) | ((unsigned)f2bf(n1 - bf2f(h1)) << 16);
      size_t cb = (size_t)t*CSTEP + (bid<<10) + (um8<<4) + ukp;   // contiguous 2KB/block
      __hip_atomic_store((unsigned*)&cstate[cb],       hp, __ATOMIC_RELAXED, __HIP_MEMORY_SCOPE_AGENT);
      __hip_atomic_store((unsigned*)&cstate[cb + 512], lp, __ATOMIC_RELAXED, __HIP_MEMORY_SCOPE_AGENT);
      int rb = (um8<<10) + nb + ukp;
      *(unsigned*)&out_bf[(size_t)t*CLSLOT + rb] = hp;            // plain store, off critical path
      if (t == T_DIM-1){ hid_final[rb] = n0; hid_final[rb+1] = n1; }
    }
    if (t < T_DIM-1){
      __syncthreads();   // per-wave vmcnt(0): all sc1 stores at coherence point
      if (tid == 0)
        __hip_atomic_store(&slots[bid], (unsigned)(t+1), __ATOMIC_RELAXED, __HIP_MEMORY_SCOPE_AGENT);
      // prefetch next step's x/ixfx while waiting (barrier-independent)
      {
        const float* x_t  = x_all + (size_t)(t+1)*CLSLOT;
        const float* ix_t = ixfx  + (size_t)(t+1)*(B_DIM*2048);
        if (tid < 256) xv2 = *(const float2*)&x_t[(um8<<10) + nb + ukp];
        if (kh == 0){
          #pragma unroll
          for (int q = 0; q < 4; ++q){
            int m = (mh<<4) + ((lane>>4)<<2) + q;
            pix[q] = ix_t[m*2048 + (gate<<10) + nb + ar];
          }
        }
      }
      if (wid == 0){
        unsigned tgt = (unsigned)(t+1);
        while (1){
          unsigned v = __hip_atomic_load(&slots[lane], __ATOMIC_RELAXED, __HIP_MEMORY_SCOPE_AGENT);
          if (__ballot(v < tgt) == 0ull) break;
          __builtin_amdgcn_s_sleep(1);
        }
      }
      __syncthreads();
    }
  }
}

__global__ void init_c_kernel(const float* __restrict__ hidden,
                              ushort* __restrict__ cinit, unsigned* __restrict__ slots){
  int i = blockIdx.x * blockDim.x + threadIdx.x;   // 0..32767
  if (blockIdx.x == 0 && threadIdx.x < NBLK) slots[threadIdx.x] = 0;
  float v = hidden[i];
  ushort h = f2bf(v);
  ushort l = f2bf(v - bf2f(h));
  int m = i >> 10, col = i & 1023;
  int j = col >> 4, k = col & 15;
  cinit[(j<<10) + (m<<4) + k]       = h;
  cinit[(j<<10) + (m<<4) + k + 512] = l;
}

// ---------------- lse reduce + subtract ----------------
__global__ __launch_bounds__(64) void lse_reduce(const float* __restrict__ pmax,
                                                 const float* __restrict__ psum,
                                                 float* __restrict__ lse, int ntn){
  int row = blockIdx.x, lane = threadIdx.x;
  float m = -1e30f, s = 0.f;
  for (int i = lane; i < ntn; i += 64){
    float mi = pmax[(size_t)row*ntn + i], si = psum[(size_t)row*ntn + i];
    float M = fmaxf(m, mi);
    s = s*expf(m - M) + si*expf(mi - M);
    m = M;
  }
  #pragma unroll
  for (int o = 32; o; o >>= 1){
    float m2 = __shfl_xor(m, o), s2 = __shfl_xor(s, o);
    float M = fmaxf(m, m2);
    s = s*expf(m - M) + s2*expf(m2 - M);
    m = M;
  }
  if (lane == 0) lse[row] = m + logf(s);
}

__global__ __launch_bounds__(256) void sub_kernel(float* __restrict__ logits,
                                                  const float* __restrict__ lse){
  size_t row = blockIdx.x;
  float l = lse[row];
  float4* p4 = (float4*)(logits + row * (size_t)V_DIM);
  for (int i = threadIdx.x; i < V_DIM/4; i += 256){
    float4 v = p4[i];
    v.x -= l; v.y -= l; v.z -= l; v.w -= l;
    p4[i] = v;
  }
}

// ---------------- launch ----------------
extern "C" void kernel_launch(void* const* d_in, const int* in_sizes, int n_in,
                              void* d_out, int out_size, void* d_ws, size_t ws_size,
                              hipStream_t stream)
{
  const float* input  = (const float*)d_in[0];
  const float* hidden = (const float*)d_in[1];
  const float* w_ic   = (const float*)d_in[2];
  const float* w_ix   = (const float*)d_in[3];
  const float* w_fc   = (const float*)d_in[4];
  const float* w_fx   = (const float*)d_in[5];
  const float* b_i    = (const float*)d_in[6];
  const float* b_f    = (const float*)d_in[7];
  const float* W_out  = (const float*)d_in[8];
  const float* b_out  = (const float*)d_in[9];
  float* out = (float*)d_out;

  char* ws = (char*)d_ws;
  ushort* wout_bf = (ushort*)(ws + 0);          // 65,536,000
  ushort* in_hi   = (ushort*)(ws + 65536000);   // cast targets (dead after split-gemm)
  ushort* in_lo   = (ushort*)(ws + 73924608);
  ushort* wx_hi   = (ushort*)(ws + 82313216);
  ushort* wx_lo   = (ushort*)(ws + 86507520);
  ushort* wc_hi   = (ushort*)(ws + 90701824);
  ushort* wc_lo   = (ushort*)(ws + 94896128);
  ushort* out_bf  = (ushort*)(ws + 99090432);   // row-major bf16(c_t), all T
  unsigned* slots = (unsigned*)(ws + 107479040);
  ushort* cinit   = (ushort*)(ws + 107479296);  // chunked init c (128 KB)
  // overlays (regions dead at time of use):
  ushort* cstate  = in_hi;                      // [T][CSTEP] chunked c-state, 16,777,216 B
  float*  pmax    = (float*)(ws + 65536000);    // [4096][250] after ran_all
  float*  psum    = (float*)(ws + 69632000);
  float*  lse     = (float*)wx_hi;              // [4096]
  float*  ixfx    = out;                        // [4096][2048] scratch in logits region

  cast_bf16_kernel <<<2048,256,0,stream>>>(W_out, wout_bf, V_DIM*H_DIM/4);
  cast_split_kernel<<<1024,256,0,stream>>>(input, in_hi, in_lo, MROWS*H_DIM/4);
  cast_split_kernel<<<256,256,0,stream>>>(w_ix, wx_hi,             wx_lo,             H_DIM*H_DIM/4);
  cast_split_kernel<<<256,256,0,stream>>>(w_fx, wx_hi+H_DIM*H_DIM, wx_lo+H_DIM*H_DIM, H_DIM*H_DIM/4);
  cast_split_kernel<<<256,256,0,stream>>>(w_ic, wc_hi,             wc_lo,             H_DIM*H_DIM/4);
  cast_split_kernel<<<256,256,0,stream>>>(w_fc, wc_hi+H_DIM*H_DIM, wc_lo+H_DIM*H_DIM, H_DIM*H_DIM/4);

  // ixfx = input @ [w_ix; w_fx]^T (split-bf16, fused)
  gemm_bt_split<<<32*16,256,0,stream>>>(in_hi, in_lo, wx_hi, wx_lo, ixfx, 2048, H_DIM, 16);

  init_c_kernel<<<128,256,0,stream>>>(hidden, cinit, slots);

  ran_all2<<<NBLK,512,0,stream>>>(cinit, cstate, hidden, wc_hi, wc_lo, b_i, b_f,
                                  ixfx, input, out_bf, out + (size_t)MROWS*V_DIM, slots);

  // logits + fused LSE partials
  gemm_bt<<<32*250,256,0,stream>>>(out_bf, wout_bf, out, b_out, V_DIM, H_DIM, 250, 1, pmax, psum);
  lse_reduce<<<MROWS,64,0,stream>>>(pmax, psum, lse, 250);
  sub_kernel<<<MROWS,256,0,stream>>>(out, lse);
}

// Round 6
// 2045.286 us; speedup vs baseline: 1.0031x; 1.0031x over previous
//
#include <hip/hip_runtime.h>

typedef __attribute__((ext_vector_type(4))) float f32x4;
typedef __attribute__((ext_vector_type(8))) short bf16x8;

#define T_DIM 128
#define B_DIM 32
#define H_DIM 1024
#define V_DIM 32000
#define MROWS 4096   // T*B
#define NBLK 64      // persistent recurrence blocks
#define CSTEP 32768  // elements per t in chunked c-state: 64 chunks x (32m x 16k)
#define WSTRIDE 1028 // LDS W row stride (ushorts): bank step 2 -> conflict-free

__device__ __forceinline__ ushort f2bf(float f){
  union { float f; unsigned u; } x; x.f = f;
  unsigned u = x.u;
  unsigned r = (u + 0x7fffu + ((u >> 16) & 1u)) >> 16;
  return (ushort)r;
}
__device__ __forceinline__ float bf2f(ushort h){
  union { unsigned u; float f; } x; x.u = ((unsigned)h) << 16;
  return x.f;
}

__device__ __forceinline__ void async_copy16(void* lds, const void* g){
  __builtin_amdgcn_global_load_lds((const __attribute__((address_space(1))) void*)g,
                                   (__attribute__((address_space(3))) void*)lds, 16, 0, 0);
}

// ---------------- casts ----------------
__global__ void cast_bf16_kernel(const float* __restrict__ s, ushort* __restrict__ d, int n4){
  int stride = gridDim.x * blockDim.x;
  for (int i = blockIdx.x*blockDim.x + threadIdx.x; i < n4; i += stride){
    float4 v = ((const float4*)s)[i];
    ushort4 o = make_ushort4(f2bf(v.x), f2bf(v.y), f2bf(v.z), f2bf(v.w));
    ((ushort4*)d)[i] = o;
  }
}

__global__ void cast_split_kernel(const float* __restrict__ s, ushort* __restrict__ dh,
                                  ushort* __restrict__ dl, int n4){
  int stride = gridDim.x * blockDim.x;
  for (int i = blockIdx.x*blockDim.x + threadIdx.x; i < n4; i += stride){
    float4 v = ((const float4*)s)[i];
    ushort4 h = make_ushort4(f2bf(v.x), f2bf(v.y), f2bf(v.z), f2bf(v.w));
    ushort4 l = make_ushort4(f2bf(v.x - bf2f(h.x)), f2bf(v.y - bf2f(h.y)),
                             f2bf(v.z - bf2f(h.z)), f2bf(v.w - bf2f(h.w)));
    ((ushort4*)dh)[i] = h;
    ((ushort4*)dl)[i] = l;
  }
}

// ---------------- m97-style bf16 GEMM + optional fused LSE partials ----------------
// C[M][N] = A[M][K]*B[N][K]^T + bias. order==1: XCD-banded (gridDim%8==0, 32 M-tiles).
// achunk==1: A is in chunked c-state layout [t][k>>4][m][k&15] (t=row>>5, m=row&31).
__global__ __launch_bounds__(256) void gemm_bt(
    const ushort* __restrict__ A, const ushort* __restrict__ B,
    float* __restrict__ C, const float* __restrict__ bias,
    int N, int K, int NTN, int order, int achunk,
    float* __restrict__ pmax, float* __restrict__ psum)
{
  __shared__ ushort lA[128*32];
  __shared__ ushort lB[128*32];
  __shared__ float pmS[4][64], psS[4][64];
  int tid = threadIdx.x;
  int lane = tid & 63, wid = tid >> 6;
  int bid = blockIdx.x;
  int tm, tn;
  if (order){
    int xcd = bid & 7, id = bid >> 3;
    tn = id >> 2;                 // B tile fetched once per XCD
    tm = (xcd << 2) | (id & 3);   // 4-tm A band resident per XCD L2
  } else {
    tm = bid / NTN; tn = bid % NTN;
  }
  int row0 = tm << 7, col0 = tn << 7;

  f32x4 acc[4][4] = {};

  auto stage = [&](const ushort* __restrict__ g, ushort* l, int r0, int k0){
    int c = wid << 1;
    const ushort* s0 = g + (size_t)(r0 + (c<<4) + (lane>>2))*K + k0 + ((lane&3)<<3);
    async_copy16(l + (c<<9), s0);
    async_copy16(l + ((c+1)<<9), s0 + (size_t)16*K);
  };
  // chunked A stage: same lane->(row,k) map, source address remapped to chunk layout
  auto stageAc = [&](const ushort* __restrict__ g, ushort* l, int r0, int k0){
    int c = wid << 1;
    int cb  = (k0 >> 4) + ((lane & 3) >> 1);
    int sub = (lane & 1) << 3;
    int rA = r0 + (c<<4) + (lane>>2);
    const ushort* sA = g + ((size_t)(rA>>5)<<15) + (cb<<9) + ((rA&31)<<4) + sub;
    async_copy16(l + (c<<9), sA);
    int rB = rA + 16;
    const ushort* sB = g + ((size_t)(rB>>5)<<15) + (cb<<9) + ((rB&31)<<4) + sub;
    async_copy16(l + ((c+1)<<9), sB);
  };

  int nk = K >> 5;
  if (achunk) stageAc(A, lA, row0, 0); else stage(A, lA, row0, 0);
  stage(B, lB, col0, 0);
  int wm = (wid >> 1) << 6, wn = (wid & 1) << 6;
  int kg = (lane >> 4) << 3;
  int ar = lane & 15;

  for (int kt = 0; kt < nk; ++kt){
    __syncthreads();
    bf16x8 af[4], bfr[4];
    #pragma unroll
    for (int mi = 0; mi < 4; ++mi) af[mi]  = *(const bf16x8*)&lA[(wm + mi*16 + ar)*32 + kg];
    #pragma unroll
    for (int ni = 0; ni < 4; ++ni) bfr[ni] = *(const bf16x8*)&lB[(wn + ni*16 + ar)*32 + kg];
    #pragma unroll
    for (int mi = 0; mi < 4; ++mi)
      #pragma unroll
      for (int ni = 0; ni < 4; ++ni)
        acc[mi][ni] = __builtin_amdgcn_mfma_f32_16x16x32_bf16(af[mi], bfr[ni], acc[mi][ni], 0, 0, 0);
    if (kt + 1 < nk){
      __syncthreads();
      if (achunk) stageAc(A, lA, row0, (kt+1) << 5); else stage(A, lA, row0, (kt+1) << 5);
      stage(B, lB, col0, (kt+1) << 5);
    }
  }

  int rr = (lane >> 4) << 2;
  float bb4[4];
  #pragma unroll
  for (int ni = 0; ni < 4; ++ni) bb4[ni] = bias ? bias[col0 + wn + ni*16 + ar] : 0.f;

  #pragma unroll
  for (int mi = 0; mi < 4; ++mi){
    #pragma unroll
    for (int q = 0; q < 4; ++q){
      int r = row0 + wm + mi*16 + rr + q;
      float vals[4];
      #pragma unroll
      for (int ni = 0; ni < 4; ++ni){
        vals[ni] = acc[mi][ni][q] + bb4[ni];
        C[(size_t)r * N + col0 + wn + ni*16 + ar] = vals[ni];
      }
      if (pmax){
        float m = fmaxf(fmaxf(vals[0], vals[1]), fmaxf(vals[2], vals[3]));
        #pragma unroll
        for (int o = 1; o < 16; o <<= 1) m = fmaxf(m, __shfl_xor(m, o));
        float s = expf(vals[0]-m) + expf(vals[1]-m) + expf(vals[2]-m) + expf(vals[3]-m);
        #pragma unroll
        for (int o = 1; o < 16; o <<= 1) s += __shfl_xor(s, o);
        if (ar == 0){ int rl = mi*16 + rr + q; pmS[wid][rl] = m; psS[wid][rl] = s; }
      }
    }
  }
  if (pmax){
    __syncthreads();
    if (tid < 128){
      int rl = tid & 63, half = tid >> 6;
      int w0 = half*2, w1 = w0 + 1;
      float m0 = pmS[w0][rl], m1 = pmS[w1][rl];
      float s0 = psS[w0][rl], s1 = psS[w1][rl];
      float M = fmaxf(m0, m1);
      float S = s0*expf(m0-M) + s1*expf(m1-M);
      int r = row0 + half*64 + rl;
      pmax[(size_t)r*NTN + tn] = M;
      psum[(size_t)r*NTN + tn] = S;
    }
  }
}

// ---------------- fused split-bf16 GEMM: C = Ah*Bh^T + Ah*Bl^T + Al*Bh^T ----------------
__global__ __launch_bounds__(256) void gemm_bt_split(
    const ushort* __restrict__ Ah, const ushort* __restrict__ Al,
    const ushort* __restrict__ Bh, const ushort* __restrict__ Bl,
    float* __restrict__ C, int N, int K, int NTN)
{
  __shared__ ushort lAh[128*32], lAl[128*32], lBh[128*32], lBl[128*32];
  int tid = threadIdx.x;
  int lane = tid & 63, wid = tid >> 6;
  int tm = blockIdx.x / NTN, tn = blockIdx.x % NTN;
  int row0 = tm << 7, col0 = tn << 7;

  f32x4 acc[4][4] = {};

  auto stage = [&](const ushort* __restrict__ g, ushort* l, int r0, int k0){
    int c = wid << 1;
    const ushort* s0 = g + (size_t)(r0 + (c<<4) + (lane>>2))*K + k0 + ((lane&3)<<3);
    async_copy16(l + (c<<9), s0);
    async_copy16(l + ((c+1)<<9), s0 + (size_t)16*K);
  };

  int nk = K >> 5;
  stage(Ah, lAh, row0, 0); stage(Al, lAl, row0, 0);
  stage(Bh, lBh, col0, 0); stage(Bl, lBl, col0, 0);
  int wm = (wid >> 1) << 6, wn = (wid & 1) << 6;
  int kg = (lane >> 4) << 3;
  int ar = lane & 15;

  for (int kt = 0; kt < nk; ++kt){
    __syncthreads();
    bf16x8 afh[4], afl[4], bfh[4], bfl[4];
    #pragma unroll
    for (int mi = 0; mi < 4; ++mi){
      afh[mi] = *(const bf16x8*)&lAh[(wm + mi*16 + ar)*32 + kg];
      afl[mi] = *(const bf16x8*)&lAl[(wm + mi*16 + ar)*32 + kg];
    }
    #pragma unroll
    for (int ni = 0; ni < 4; ++ni){
      bfh[ni] = *(const bf16x8*)&lBh[(wn + ni*16 + ar)*32 + kg];
      bfl[ni] = *(const bf16x8*)&lBl[(wn + ni*16 + ar)*32 + kg];
    }
    #pragma unroll
    for (int mi = 0; mi < 4; ++mi)
      #pragma unroll
      for (int ni = 0; ni < 4; ++ni){
        acc[mi][ni] = __builtin_amdgcn_mfma_f32_16x16x32_bf16(afh[mi], bfh[ni], acc[mi][ni], 0, 0, 0);
        acc[mi][ni] = __builtin_amdgcn_mfma_f32_16x16x32_bf16(afh[mi], bfl[ni], acc[mi][ni], 0, 0, 0);
        acc[mi][ni] = __builtin_amdgcn_mfma_f32_16x16x32_bf16(afl[mi], bfh[ni], acc[mi][ni], 0, 0, 0);
      }
    if (kt + 1 < nk){
      __syncthreads();
      stage(Ah, lAh, row0, (kt+1) << 5); stage(Al, lAl, row0, (kt+1) << 5);
      stage(Bh, lBh, col0, (kt+1) << 5); stage(Bl, lBl, col0, (kt+1) << 5);
    }
  }

  int rr = (lane >> 4) << 2;
  #pragma unroll
  for (int mi = 0; mi < 4; ++mi)
    #pragma unroll
    for (int ni = 0; ni < 4; ++ni){
      int r  = row0 + wm + mi*16 + rr;
      int cc = col0 + wn + ni*16 + ar;
      #pragma unroll
      for (int q = 0; q < 4; ++q)
        C[(size_t)(r + q) * N + cc] = acc[mi][ni][q];
    }
}

// ---------------- persistent recurrence v5 ----------------
// Published state per step per block: ONE contiguous 1 KB chunk of bf16 c-hi.
// No lo-stream, no row-major epilogue stores, nothing else in the pre-signal drain.
// MFMA streams: a0 = c_hi x W_hi, a1 = c_hi x W_lo (W split kept for accuracy).
__global__ __launch_bounds__(512) void ran_all(
    const ushort* __restrict__ cinit, ushort* __restrict__ cstate,
    const float* __restrict__ hiddenf,
    const ushort* __restrict__ wh, const ushort* __restrict__ wl,
    const float* __restrict__ b_i, const float* __restrict__ b_f,
    const float* __restrict__ ixfx, const float* __restrict__ x_all,
    float* __restrict__ hid_final, unsigned* __restrict__ slots)
{
  __shared__ ushort lWh[32*WSTRIDE];
  __shared__ ushort lWl[32*WSTRIDE];
  __shared__ float part[8][64][4];
  __shared__ float gsm[2*32*17];
  __shared__ float cfl[32][17];

  int tid = threadIdx.x, lane = tid & 63, wid = tid >> 6;
  int kh = wid & 1, mh = (wid >> 1) & 1, gate = wid >> 2;
  int bid = blockIdx.x;
  int nb = bid << 4;
  int ar = lane & 15, kg = (lane >> 4) << 3;
  int um8 = tid >> 3, ukp = (tid & 7) << 1;

  // one-time: W slice -> LDS (hi+lo), c f32 slice -> LDS
  #pragma unroll
  for (int u = 0; u < 8; ++u){
    int unit = u*512 + tid;
    int r = unit >> 7, off = (unit & 127) << 3;
    int g = r >> 4, c = r & 15;
    size_t gsrc = (size_t)((g<<10) + nb + c) * H_DIM + off;
    *(bf16x8*)&lWh[r*WSTRIDE + off] = *(const bf16x8*)&wh[gsrc];
    *(bf16x8*)&lWl[r*WSTRIDE + off] = *(const bf16x8*)&wl[gsrc];
  }
  if (tid < 256){
    cfl[um8][ukp]   = hiddenf[(um8<<10) + nb + ukp];
    cfl[um8][ukp+1] = hiddenf[(um8<<10) + nb + ukp + 1];
  }
  float bb = (gate ? b_f : b_i)[nb + ar];
  const ushort* bbase_h = &lWh[((gate<<4) + ar)*WSTRIDE + (kh<<9)];
  const ushort* bbase_l = &lWl[((gate<<4) + ar)*WSTRIDE + (kh<<9)];
  // chunked A base: k = kh*512 + kk*32 + kg -> addr = (kh<<14)+(kk<<10)+((kg>>4)<<9)+(m<<4)+(kg&8)
  int abase = (kh<<14) + ((kg>>4)<<9) + (((mh<<4) + ar)<<4) + (kg & 8);
  __syncthreads();

  // prefetch t=0 read-only per-step data
  float2 xv2; float pix[4];
  if (tid < 256) xv2 = *(const float2*)&x_all[(um8<<10) + nb + ukp];
  if (kh == 0){
    #pragma unroll
    for (int q = 0; q < 4; ++q){
      int m = (mh<<4) + ((lane>>4)<<2) + q;
      pix[q] = ixfx[m*2048 + (gate<<10) + nb + ar];
    }
  }

  for (int t = 0; t < T_DIM; ++t){
    const ushort* cst = t ? cstate + (size_t)(t-1)*CSTEP : cinit;

    f32x4 a0 = {}, a1 = {};
    #pragma unroll 4
    for (int kk = 0; kk < 16; ++kk){
      int oa = abase + (kk<<10);
      int ob = (kk<<5) + kg;
      bf16x8 vah = *(const bf16x8*)&cst[oa];
      bf16x8 vbh = *(const bf16x8*)&bbase_h[ob];
      bf16x8 vbl = *(const bf16x8*)&bbase_l[ob];
      a0 = __builtin_amdgcn_mfma_f32_16x16x32_bf16(vah, vbh, a0, 0, 0, 0);
      a1 = __builtin_amdgcn_mfma_f32_16x16x32_bf16(vah, vbl, a1, 0, 0, 0);
    }
    f32x4 acc = a0 + a1;
    *(f32x4*)&part[wid][lane][0] = acc;
    __syncthreads();
    if (kh == 0){
      f32x4 sum = *(const f32x4*)&part[wid][lane][0] + *(const f32x4*)&part[wid+1][lane][0];
      #pragma unroll
      for (int q = 0; q < 4; ++q){
        int m = (mh<<4) + ((lane>>4)<<2) + q;
        float pre = sum[q] + bb + pix[q];
        gsm[((gate<<5) + m)*17 + ar] = 1.f / (1.f + expf(-pre));
      }
    }
    __syncthreads();
    if (tid < 256){
      float iv0 = gsm[um8*17 + ukp],       iv1 = gsm[um8*17 + ukp + 1];
      float fv0 = gsm[(32+um8)*17 + ukp],  fv1 = gsm[(32+um8)*17 + ukp + 1];
      float c0 = cfl[um8][ukp], c1 = cfl[um8][ukp+1];
      float n0 = iv0*xv2.x + fv0*c0;
      float n1 = iv1*xv2.y + fv1*c1;
      cfl[um8][ukp] = n0; cfl[um8][ukp+1] = n1;
      unsigned hp = (unsigned)f2bf(n0) | ((unsigned)f2bf(n1) << 16);
      size_t cb = (size_t)t*CSTEP + (bid<<9) + (um8<<4) + ukp;  // contiguous 1 KB/block
      __hip_atomic_store((unsigned*)&cstate[cb], hp, __ATOMIC_RELAXED, __HIP_MEMORY_SCOPE_AGENT);
      if (t == T_DIM-1){
        int rb = (um8<<10) + nb + ukp;
        hid_final[rb] = n0; hid_final[rb+1] = n1;
      }
    }
    if (t < T_DIM-1){
      __syncthreads();   // drains each wave's 1 KB sc1 store (vmcnt 0) + LDS sync
      if (tid == 0)
        __hip_atomic_store(&slots[bid], (unsigned)(t+1), __ATOMIC_RELAXED, __HIP_MEMORY_SCOPE_AGENT);
      // prefetch next step's x/ixfx while waiting (barrier-independent)
      {
        const float* x_t  = x_all + (size_t)(t+1)*(B_DIM*H_DIM);
        const float* ix_t = ixfx  + (size_t)(t+1)*(B_DIM*2048);
        if (tid < 256) xv2 = *(const float2*)&x_t[(um8<<10) + nb + ukp];
        if (kh == 0){
          #pragma unroll
          for (int q = 0; q < 4; ++q){
            int m = (mh<<4) + ((lane>>4)<<2) + q;
            pix[q] = ix_t[m*2048 + (gate<<10) + nb + ar];
          }
        }
      }
      if (wid == 0){
        unsigned tgt = (unsigned)(t+1);
        while (1){
          unsigned v = __hip_atomic_load(&slots[lane], __ATOMIC_RELAXED, __HIP_MEMORY_SCOPE_AGENT);
          if (__ballot(v < tgt) == 0ull) break;
          __builtin_amdgcn_s_sleep(1);
        }
      }
      __syncthreads();
    }
  }
}

__global__ void init_c_kernel(const float* __restrict__ hidden,
                              ushort* __restrict__ cinit, unsigned* __restrict__ slots){
  int i = blockIdx.x * blockDim.x + threadIdx.x;   // 0..32767
  if (blockIdx.x == 0 && threadIdx.x < NBLK) slots[threadIdx.x] = 0;
  float v = hidden[i];
  int m = i >> 10, col = i & 1023;
  cinit[((col>>4)<<9) + (m<<4) + (col&15)] = f2bf(v);
}

// ---------------- lse reduce + subtract ----------------
__global__ __launch_bounds__(64) void lse_reduce(const float* __restrict__ pmax,
                                                 const float* __restrict__ psum,
                                                 float* __restrict__ lse, int ntn){
  int row = blockIdx.x, lane = threadIdx.x;
  float m = -1e30f, s = 0.f;
  for (int i = lane; i < ntn; i += 64){
    float mi = pmax[(size_t)row*ntn + i], si = psum[(size_t)row*ntn + i];
    float M = fmaxf(m, mi);
    s = s*expf(m - M) + si*expf(mi - M);
    m = M;
  }
  #pragma unroll
  for (int o = 32; o; o >>= 1){
    float m2 = __shfl_xor(m, o), s2 = __shfl_xor(s, o);
    float M = fmaxf(m, m2);
    s = s*expf(m - M) + s2*expf(m2 - M);
    m = M;
  }
  if (lane == 0) lse[row] = m + logf(s);
}

__global__ __launch_bounds__(256) void sub_kernel(float* __restrict__ logits,
                                                  const float* __restrict__ lse){
  size_t row = blockIdx.x;
  float l = lse[row];
  float4* p4 = (float4*)(logits + row * (size_t)V_DIM);
  for (int i = threadIdx.x; i < V_DIM/4; i += 256){
    float4 v = p4[i];
    v.x -= l; v.y -= l; v.z -= l; v.w -= l;
    p4[i] = v;
  }
}

// ---------------- launch ----------------
extern "C" void kernel_launch(void* const* d_in, const int* in_sizes, int n_in,
                              void* d_out, int out_size, void* d_ws, size_t ws_size,
                              hipStream_t stream)
{
  const float* input  = (const float*)d_in[0];
  const float* hidden = (const float*)d_in[1];
  const float* w_ic   = (const float*)d_in[2];
  const float* w_ix   = (const float*)d_in[3];
  const float* w_fc   = (const float*)d_in[4];
  const float* w_fx   = (const float*)d_in[5];
  const float* b_i    = (const float*)d_in[6];
  const float* b_f    = (const float*)d_in[7];
  const float* W_out  = (const float*)d_in[8];
  const float* b_out  = (const float*)d_in[9];
  float* out = (float*)d_out;

  char* ws = (char*)d_ws;
  ushort* wout_bf = (ushort*)(ws + 0);          // 65,536,000
  ushort* in_hi   = (ushort*)(ws + 65536000);   // cast targets (dead after split-gemm)
  ushort* in_lo   = (ushort*)(ws + 73924608);
  ushort* wx_hi   = (ushort*)(ws + 82313216);
  ushort* wx_lo   = (ushort*)(ws + 86507520);
  ushort* wc_hi   = (ushort*)(ws + 90701824);
  ushort* wc_lo   = (ushort*)(ws + 94896128);
  unsigned* slots = (unsigned*)(ws + 107479040);
  ushort* cinit   = (ushort*)(ws + 107479296);  // chunked init c-hi (64 KB)
  // overlays (regions dead at time of use):
  ushort* cstate  = in_hi;                      // [T][CSTEP] chunked c-hi, 8,388,608 B
  float*  pmax    = (float*)in_lo;              // [4096][250] (after split-gemm)
  float*  psum    = (float*)(ws + 78020608);
  float*  lse     = (float*)wx_hi;              // [4096]
  float*  ixfx    = out;                        // [4096][2048] scratch in logits region

  cast_bf16_kernel <<<2048,256,0,stream>>>(W_out, wout_bf, V_DIM*H_DIM/4);
  cast_split_kernel<<<1024,256,0,stream>>>(input, in_hi, in_lo, MROWS*H_DIM/4);
  cast_split_kernel<<<256,256,0,stream>>>(w_ix, wx_hi,             wx_lo,             H_DIM*H_DIM/4);
  cast_split_kernel<<<256,256,0,stream>>>(w_fx, wx_hi+H_DIM*H_DIM, wx_lo+H_DIM*H_DIM, H_DIM*H_DIM/4);
  cast_split_kernel<<<256,256,0,stream>>>(w_ic, wc_hi,             wc_lo,             H_DIM*H_DIM/4);
  cast_split_kernel<<<256,256,0,stream>>>(w_fc, wc_hi+H_DIM*H_DIM, wc_lo+H_DIM*H_DIM, H_DIM*H_DIM/4);

  // ixfx = input @ [w_ix; w_fx]^T (split-bf16, fused)
  gemm_bt_split<<<32*16,256,0,stream>>>(in_hi, in_lo, wx_hi, wx_lo, ixfx, 2048, H_DIM, 16);

  init_c_kernel<<<128,256,0,stream>>>(hidden, cinit, slots);

  ran_all<<<NBLK,512,0,stream>>>(cinit, cstate, hidden, wc_hi, wc_lo, b_i, b_f,
                                 ixfx, input, out + (size_t)MROWS*V_DIM, slots);

  // logits + fused LSE partials; A staged directly from chunked c-state
  gemm_bt<<<32*250,256,0,stream>>>(cstate, wout_bf, out, b_out, V_DIM, H_DIM, 250, 1, 1, pmax, psum);
  lse_reduce<<<MROWS,64,0,stream>>>(pmax, psum, lse, 250);
  sub_kernel<<<MROWS,256,0,stream>>>(out, lse);
}

// Round 7
// 2037.026 us; speedup vs baseline: 1.0072x; 1.0041x over previous
//
#include <hip/hip_runtime.h>

typedef __attribute__((ext_vector_type(4))) float f32x4;
typedef __attribute__((ext_vector_type(8))) short bf16x8;

#define T_DIM 128
#define B_DIM 32
#define H_DIM 1024
#define V_DIM 32000
#define MROWS 4096   // T*B
#define NBLK 64      // persistent recurrence blocks
#define CSTEP 32768  // elements per t in chunked c-state: 64 chunks x (32m x 16k)
#define WSTRIDE 1028 // LDS W row stride (ushorts): bank step 2 -> conflict-free

__device__ __forceinline__ ushort f2bf(float f){
  union { float f; unsigned u; } x; x.f = f;
  unsigned u = x.u;
  unsigned r = (u + 0x7fffu + ((u >> 16) & 1u)) >> 16;
  return (ushort)r;
}
__device__ __forceinline__ float bf2f(ushort h){
  union { unsigned u; float f; } x; x.u = ((unsigned)h) << 16;
  return x.f;
}

__device__ __forceinline__ void async_copy16(void* lds, const void* g){
  __builtin_amdgcn_global_load_lds((const __attribute__((address_space(1))) void*)g,
                                   (__attribute__((address_space(3))) void*)lds, 16, 0, 0);
}

// ---------------- casts ----------------
__global__ void cast_bf16_kernel(const float* __restrict__ s, ushort* __restrict__ d, int n4){
  int stride = gridDim.x * blockDim.x;
  for (int i = blockIdx.x*blockDim.x + threadIdx.x; i < n4; i += stride){
    float4 v = ((const float4*)s)[i];
    ushort4 o = make_ushort4(f2bf(v.x), f2bf(v.y), f2bf(v.z), f2bf(v.w));
    ((ushort4*)d)[i] = o;
  }
}

__global__ void cast_split_kernel(const float* __restrict__ s, ushort* __restrict__ dh,
                                  ushort* __restrict__ dl, int n4){
  int stride = gridDim.x * blockDim.x;
  for (int i = blockIdx.x*blockDim.x + threadIdx.x; i < n4; i += stride){
    float4 v = ((const float4*)s)[i];
    ushort4 h = make_ushort4(f2bf(v.x), f2bf(v.y), f2bf(v.z), f2bf(v.w));
    ushort4 l = make_ushort4(f2bf(v.x - bf2f(h.x)), f2bf(v.y - bf2f(h.y)),
                             f2bf(v.z - bf2f(h.z)), f2bf(v.w - bf2f(h.w)));
    ((ushort4*)dh)[i] = h;
    ((ushort4*)dl)[i] = l;
  }
}

// ---------------- m97-style bf16 GEMM + optional fused LSE partials ----------------
// C[M][N] = A[M][K]*B[N][K]^T + bias. order==1: XCD-banded (gridDim%8==0, 32 M-tiles).
// achunk==1: A is in chunked c-state layout [t][k>>4][m][k&15] (t=row>>5, m=row&31).
__global__ __launch_bounds__(256) void gemm_bt(
    const ushort* __restrict__ A, const ushort* __restrict__ B,
    float* __restrict__ C, const float* __restrict__ bias,
    int N, int K, int NTN, int order, int achunk,
    float* __restrict__ pmax, float* __restrict__ psum)
{
  __shared__ ushort lA[128*32];
  __shared__ ushort lB[128*32];
  __shared__ float pmS[4][64], psS[4][64];
  int tid = threadIdx.x;
  int lane = tid & 63, wid = tid >> 6;
  int bid = blockIdx.x;
  int tm, tn;
  if (order){
    int xcd = bid & 7, id = bid >> 3;
    tn = id >> 2;                 // B tile fetched once per XCD
    tm = (xcd << 2) | (id & 3);   // 4-tm A band resident per XCD L2
  } else {
    tm = bid / NTN; tn = bid % NTN;
  }
  int row0 = tm << 7, col0 = tn << 7;

  f32x4 acc[4][4] = {};

  auto stage = [&](const ushort* __restrict__ g, ushort* l, int r0, int k0){
    int c = wid << 1;
    const ushort* s0 = g + (size_t)(r0 + (c<<4) + (lane>>2))*K + k0 + ((lane&3)<<3);
    async_copy16(l + (c<<9), s0);
    async_copy16(l + ((c+1)<<9), s0 + (size_t)16*K);
  };
  // chunked A stage: same lane->(row,k) map, source address remapped to chunk layout
  auto stageAc = [&](const ushort* __restrict__ g, ushort* l, int r0, int k0){
    int c = wid << 1;
    int cb  = (k0 >> 4) + ((lane & 3) >> 1);
    int sub = (lane & 1) << 3;
    int rA = r0 + (c<<4) + (lane>>2);
    const ushort* sA = g + ((size_t)(rA>>5)<<15) + (cb<<9) + ((rA&31)<<4) + sub;
    async_copy16(l + (c<<9), sA);
    int rB = rA + 16;
    const ushort* sB = g + ((size_t)(rB>>5)<<15) + (cb<<9) + ((rB&31)<<4) + sub;
    async_copy16(l + ((c+1)<<9), sB);
  };

  int nk = K >> 5;
  if (achunk) stageAc(A, lA, row0, 0); else stage(A, lA, row0, 0);
  stage(B, lB, col0, 0);
  int wm = (wid >> 1) << 6, wn = (wid & 1) << 6;
  int kg = (lane >> 4) << 3;
  int ar = lane & 15;

  for (int kt = 0; kt < nk; ++kt){
    __syncthreads();
    bf16x8 af[4], bfr[4];
    #pragma unroll
    for (int mi = 0; mi < 4; ++mi) af[mi]  = *(const bf16x8*)&lA[(wm + mi*16 + ar)*32 + kg];
    #pragma unroll
    for (int ni = 0; ni < 4; ++ni) bfr[ni] = *(const bf16x8*)&lB[(wn + ni*16 + ar)*32 + kg];
    #pragma unroll
    for (int mi = 0; mi < 4; ++mi)
      #pragma unroll
      for (int ni = 0; ni < 4; ++ni)
        acc[mi][ni] = __builtin_amdgcn_mfma_f32_16x16x32_bf16(af[mi], bfr[ni], acc[mi][ni], 0, 0, 0);
    if (kt + 1 < nk){
      __syncthreads();
      if (achunk) stageAc(A, lA, row0, (kt+1) << 5); else stage(A, lA, row0, (kt+1) << 5);
      stage(B, lB, col0, (kt+1) << 5);
    }
  }

  int rr = (lane >> 4) << 2;
  float bb4[4];
  #pragma unroll
  for (int ni = 0; ni < 4; ++ni) bb4[ni] = bias ? bias[col0 + wn + ni*16 + ar] : 0.f;

  #pragma unroll
  for (int mi = 0; mi < 4; ++mi){
    #pragma unroll
    for (int q = 0; q < 4; ++q){
      int r = row0 + wm + mi*16 + rr + q;
      float vals[4];
      #pragma unroll
      for (int ni = 0; ni < 4; ++ni){
        vals[ni] = acc[mi][ni][q] + bb4[ni];
        C[(size_t)r * N + col0 + wn + ni*16 + ar] = vals[ni];
      }
      if (pmax){
        float m = fmaxf(fmaxf(vals[0], vals[1]), fmaxf(vals[2], vals[3]));
        #pragma unroll
        for (int o = 1; o < 16; o <<= 1) m = fmaxf(m, __shfl_xor(m, o));
        float s = expf(vals[0]-m) + expf(vals[1]-m) + expf(vals[2]-m) + expf(vals[3]-m);
        #pragma unroll
        for (int o = 1; o < 16; o <<= 1) s += __shfl_xor(s, o);
        if (ar == 0){ int rl = mi*16 + rr + q; pmS[wid][rl] = m; psS[wid][rl] = s; }
      }
    }
  }
  if (pmax){
    __syncthreads();
    if (tid < 128){
      int rl = tid & 63, half = tid >> 6;
      int w0 = half*2, w1 = w0 + 1;
      float m0 = pmS[w0][rl], m1 = pmS[w1][rl];
      float s0 = psS[w0][rl], s1 = psS[w1][rl];
      float M = fmaxf(m0, m1);
      float S = s0*expf(m0-M) + s1*expf(m1-M);
      int r = row0 + half*64 + rl;
      pmax[(size_t)r*NTN + tn] = M;
      psum[(size_t)r*NTN + tn] = S;
    }
  }
}

// ---------------- fused split-bf16 GEMM: C = Ah*Bh^T + Ah*Bl^T + Al*Bh^T ----------------
__global__ __launch_bounds__(256) void gemm_bt_split(
    const ushort* __restrict__ Ah, const ushort* __restrict__ Al,
    const ushort* __restrict__ Bh, const ushort* __restrict__ Bl,
    float* __restrict__ C, int N, int K, int NTN)
{
  __shared__ ushort lAh[128*32], lAl[128*32], lBh[128*32], lBl[128*32];
  int tid = threadIdx.x;
  int lane = tid & 63, wid = tid >> 6;
  int tm = blockIdx.x / NTN, tn = blockIdx.x % NTN;
  int row0 = tm << 7, col0 = tn << 7;

  f32x4 acc[4][4] = {};

  auto stage = [&](const ushort* __restrict__ g, ushort* l, int r0, int k0){
    int c = wid << 1;
    const ushort* s0 = g + (size_t)(r0 + (c<<4) + (lane>>2))*K + k0 + ((lane&3)<<3);
    async_copy16(l + (c<<9), s0);
    async_copy16(l + ((c+1)<<9), s0 + (size_t)16*K);
  };

  int nk = K >> 5;
  stage(Ah, lAh, row0, 0); stage(Al, lAl, row0, 0);
  stage(Bh, lBh, col0, 0); stage(Bl, lBl, col0, 0);
  int wm = (wid >> 1) << 6, wn = (wid & 1) << 6;
  int kg = (lane >> 4) << 3;
  int ar = lane & 15;

  for (int kt = 0; kt < nk; ++kt){
    __syncthreads();
    bf16x8 afh[4], afl[4], bfh[4], bfl[4];
    #pragma unroll
    for (int mi = 0; mi < 4; ++mi){
      afh[mi] = *(const bf16x8*)&lAh[(wm + mi*16 + ar)*32 + kg];
      afl[mi] = *(const bf16x8*)&lAl[(wm + mi*16 + ar)*32 + kg];
    }
    #pragma unroll
    for (int ni = 0; ni < 4; ++ni){
      bfh[ni] = *(const bf16x8*)&lBh[(wn + ni*16 + ar)*32 + kg];
      bfl[ni] = *(const bf16x8*)&lBl[(wn + ni*16 + ar)*32 + kg];
    }
    #pragma unroll
    for (int mi = 0; mi < 4; ++mi)
      #pragma unroll
      for (int ni = 0; ni < 4; ++ni){
        acc[mi][ni] = __builtin_amdgcn_mfma_f32_16x16x32_bf16(afh[mi], bfh[ni], acc[mi][ni], 0, 0, 0);
        acc[mi][ni] = __builtin_amdgcn_mfma_f32_16x16x32_bf16(afh[mi], bfl[ni], acc[mi][ni], 0, 0, 0);
        acc[mi][ni] = __builtin_amdgcn_mfma_f32_16x16x32_bf16(afl[mi], bfh[ni], acc[mi][ni], 0, 0, 0);
      }
    if (kt + 1 < nk){
      __syncthreads();
      stage(Ah, lAh, row0, (kt+1) << 5); stage(Al, lAl, row0, (kt+1) << 5);
      stage(Bh, lBh, col0, (kt+1) << 5); stage(Bl, lBl, col0, (kt+1) << 5);
    }
  }

  int rr = (lane >> 4) << 2;
  #pragma unroll
  for (int mi = 0; mi < 4; ++mi)
    #pragma unroll
    for (int ni = 0; ni < 4; ++ni){
      int r  = row0 + wm + mi*16 + rr;
      int cc = col0 + wn + ni*16 + ar;
      #pragma unroll
      for (int q = 0; q < 4; ++q)
        C[(size_t)(r + q) * N + cc] = acc[mi][ni][q];
    }
}

// ---------------- persistent recurrence v6: one L3 round-trip per step ----------------
// 8 waves = 4 K-quarters (kq) x 2 M-halves (mh). Each wave: 8 A-loads up front into
// registers (single vmcnt exposure), then 32 MFMAs (2 gates x W-hi/lo) from regs+LDS.
// part[4][2][2][64] LDS reduce; poll wave = wid 7 (carries no prefetch loads).
__global__ __launch_bounds__(512) void ran_all(
    const ushort* __restrict__ cinit, ushort* __restrict__ cstate,
    const float* __restrict__ hiddenf,
    const ushort* __restrict__ wh, const ushort* __restrict__ wl,
    const float* __restrict__ b_i, const float* __restrict__ b_f,
    const float* __restrict__ ixfx, const float* __restrict__ x_all,
    float* __restrict__ hid_final, unsigned* __restrict__ slots)
{
  __shared__ ushort lWh[32*WSTRIDE];
  __shared__ ushort lWl[32*WSTRIDE];
  __shared__ f32x4 part[4][2][2][64];   // [kq][mh][gate][lane]
  __shared__ float gsm[2*32*17];
  __shared__ float cfl[32][17];

  int tid = threadIdx.x, lane = tid & 63, wid = tid >> 6;
  int kq = wid & 3, mh = wid >> 2;       // MFMA-phase wave role
  int rgate = wid & 1, rmh = wid >> 1;   // reduce-phase wave role (wid<4)
  int bid = blockIdx.x;
  int nb = bid << 4;
  int ar = lane & 15, kg = (lane >> 4) << 3;
  int um8 = tid >> 3, ukp = (tid & 7) << 1;

  // one-time: W slice -> LDS (hi+lo), c f32 slice -> LDS
  #pragma unroll
  for (int u = 0; u < 8; ++u){
    int unit = u*512 + tid;
    int r = unit >> 7, off = (unit & 127) << 3;
    int g = r >> 4, c = r & 15;
    size_t gsrc = (size_t)((g<<10) + nb + c) * H_DIM + off;
    *(bf16x8*)&lWh[r*WSTRIDE + off] = *(const bf16x8*)&wh[gsrc];
    *(bf16x8*)&lWl[r*WSTRIDE + off] = *(const bf16x8*)&wl[gsrc];
  }
  if (tid < 256){
    cfl[um8][ukp]   = hiddenf[(um8<<10) + nb + ukp];
    cfl[um8][ukp+1] = hiddenf[(um8<<10) + nb + ukp + 1];
  }
  float bb = (rgate ? b_f : b_i)[nb + ar];
  // B-fragment LDS bases: W rows gate*16+ar, k-offset kq*256+kg
  const ushort* b0h = &lWh[(     ar)*WSTRIDE + (kq<<8) + kg];
  const ushort* b0l = &lWl[(     ar)*WSTRIDE + (kq<<8) + kg];
  const ushort* b1h = &lWh[(16 + ar)*WSTRIDE + (kq<<8) + kg];
  const ushort* b1l = &lWl[(16 + ar)*WSTRIDE + (kq<<8) + kg];
  // chunked A base: k = kq*256 + kk*32 + kg -> addr = chunk*512 + m*16 + (kg&8),
  // chunk = kq*16 + kk*2 + (kg>>4); m = mh*16 + ar
  int abase = (kq<<13) + ((kg>>4)<<9) + (((mh<<4) + ar)<<4) + (kg & 8);
  __syncthreads();

  // prefetch t=0 read-only per-step data
  float2 xv2; float pix[4];
  if (tid < 256) xv2 = *(const float2*)&x_all[(um8<<10) + nb + ukp];
  if (wid < 4){
    #pragma unroll
    for (int q = 0; q < 4; ++q){
      int m = (rmh<<4) + ((lane>>4)<<2) + q;
      pix[q] = ixfx[m*2048 + (rgate<<10) + nb + ar];
    }
  }

  for (int t = 0; t < T_DIM; ++t){
    const ushort* cst = t ? cstate + (size_t)(t-1)*CSTEP : cinit;

    // ---- A-loads first: 8 independent 16B loads, one latency exposure ----
    bf16x8 a[8];
    #pragma unroll
    for (int kk = 0; kk < 8; ++kk)
      a[kk] = *(const bf16x8*)&cst[abase + (kk<<10)];

    f32x4 g0h = {}, g0l = {}, g1h = {}, g1l = {};
    #pragma unroll
    for (int kk = 0; kk < 8; ++kk){
      int ob = kk << 5;
      bf16x8 w0h = *(const bf16x8*)&b0h[ob];
      bf16x8 w0l = *(const bf16x8*)&b0l[ob];
      bf16x8 w1h = *(const bf16x8*)&b1h[ob];
      bf16x8 w1l = *(const bf16x8*)&b1l[ob];
      g0h = __builtin_amdgcn_mfma_f32_16x16x32_bf16(a[kk], w0h, g0h, 0, 0, 0);
      g0l = __builtin_amdgcn_mfma_f32_16x16x32_bf16(a[kk], w0l, g0l, 0, 0, 0);
      g1h = __builtin_amdgcn_mfma_f32_16x16x32_bf16(a[kk], w1h, g1h, 0, 0, 0);
      g1l = __builtin_amdgcn_mfma_f32_16x16x32_bf16(a[kk], w1l, g1l, 0, 0, 0);
    }
    part[kq][mh][0][lane] = g0h + g0l;
    part[kq][mh][1][lane] = g1h + g1l;
    __syncthreads();

    if (wid < 4){
      f32x4 sum = part[0][rmh][rgate][lane] + part[1][rmh][rgate][lane]
                + part[2][rmh][rgate][lane] + part[3][rmh][rgate][lane];
      #pragma unroll
      for (int q = 0; q < 4; ++q){
        int m = (rmh<<4) + ((lane>>4)<<2) + q;
        float pre = sum[q] + bb + pix[q];
        gsm[((rgate<<5) + m)*17 + ar] = 1.f / (1.f + expf(-pre));
      }
    }
    __syncthreads();

    if (tid < 256){
      float iv0 = gsm[um8*17 + ukp],       iv1 = gsm[um8*17 + ukp + 1];
      float fv0 = gsm[(32+um8)*17 + ukp],  fv1 = gsm[(32+um8)*17 + ukp + 1];
      float c0 = cfl[um8][ukp], c1 = cfl[um8][ukp+1];
      float n0 = iv0*xv2.x + fv0*c0;
      float n1 = iv1*xv2.y + fv1*c1;
      cfl[um8][ukp] = n0; cfl[um8][ukp+1] = n1;
      unsigned hp = (unsigned)f2bf(n0) | ((unsigned)f2bf(n1) << 16);
      size_t cb = (size_t)t*CSTEP + (bid<<9) + (um8<<4) + ukp;  // contiguous 1 KB/block
      __hip_atomic_store((unsigned*)&cstate[cb], hp, __ATOMIC_RELAXED, __HIP_MEMORY_SCOPE_AGENT);
      if (t == T_DIM-1){
        int rb = (um8<<10) + nb + ukp;
        hid_final[rb] = n0; hid_final[rb+1] = n1;
      }
    }
    if (t < T_DIM-1){
      __syncthreads();   // drains each wave's sc1 store (vmcnt 0) + LDS sync
      if (tid == 0)
        __hip_atomic_store(&slots[bid], (unsigned)(t+1), __ATOMIC_RELAXED, __HIP_MEMORY_SCOPE_AGENT);
      // prefetch next step's x/ixfx while waiting (waves 0-3 only; poll wave stays clean)
      {
        const float* x_t  = x_all + (size_t)(t+1)*(B_DIM*H_DIM);
        const float* ix_t = ixfx  + (size_t)(t+1)*(B_DIM*2048);
        if (tid < 256) xv2 = *(const float2*)&x_t[(um8<<10) + nb + ukp];
        if (wid < 4){
          #pragma unroll
          for (int q = 0; q < 4; ++q){
            int m = (rmh<<4) + ((lane>>4)<<2) + q;
            pix[q] = ix_t[m*2048 + (rgate<<10) + nb + ar];
          }
        }
      }
      if (wid == 7){
        unsigned tgt = (unsigned)(t+1);
        while (1){
          unsigned v = __hip_atomic_load(&slots[lane], __ATOMIC_RELAXED, __HIP_MEMORY_SCOPE_AGENT);
          if (__ballot(v < tgt) == 0ull) break;
          __builtin_amdgcn_s_sleep(1);
        }
      }
      __syncthreads();
    }
  }
}

__global__ void init_c_kernel(const float* __restrict__ hidden,
                              ushort* __restrict__ cinit, unsigned* __restrict__ slots){
  int i = blockIdx.x * blockDim.x + threadIdx.x;   // 0..32767
  if (blockIdx.x == 0 && threadIdx.x < NBLK) slots[threadIdx.x] = 0;
  float v = hidden[i];
  int m = i >> 10, col = i & 1023;
  cinit[((col>>4)<<9) + (m<<4) + (col&15)] = f2bf(v);
}

// ---------------- lse reduce + subtract ----------------
__global__ __launch_bounds__(64) void lse_reduce(const float* __restrict__ pmax,
                                                 const float* __restrict__ psum,
                                                 float* __restrict__ lse, int ntn){
  int row = blockIdx.x, lane = threadIdx.x;
  float m = -1e30f, s = 0.f;
  for (int i = lane; i < ntn; i += 64){
    float mi = pmax[(size_t)row*ntn + i], si = psum[(size_t)row*ntn + i];
    float M = fmaxf(m, mi);
    s = s*expf(m - M) + si*expf(mi - M);
    m = M;
  }
  #pragma unroll
  for (int o = 32; o; o >>= 1){
    float m2 = __shfl_xor(m, o), s2 = __shfl_xor(s, o);
    float M = fmaxf(m, m2);
    s = s*expf(m - M) + s2*expf(m2 - M);
    m = M;
  }
  if (lane == 0) lse[row] = m + logf(s);
}

__global__ __launch_bounds__(256) void sub_kernel(float* __restrict__ logits,
                                                  const float* __restrict__ lse){
  size_t row = blockIdx.x;
  float l = lse[row];
  float4* p4 = (float4*)(logits + row * (size_t)V_DIM);
  for (int i = threadIdx.x; i < V_DIM/4; i += 256){
    float4 v = p4[i];
    v.x -= l; v.y -= l; v.z -= l; v.w -= l;
    p4[i] = v;
  }
}

// ---------------- launch ----------------
extern "C" void kernel_launch(void* const* d_in, const int* in_sizes, int n_in,
                              void* d_out, int out_size, void* d_ws, size_t ws_size,
                              hipStream_t stream)
{
  const float* input  = (const float*)d_in[0];
  const float* hidden = (const float*)d_in[1];
  const float* w_ic   = (const float*)d_in[2];
  const float* w_ix   = (const float*)d_in[3];
  const float* w_fc   = (const float*)d_in[4];
  const float* w_fx   = (const float*)d_in[5];
  const float* b_i    = (const float*)d_in[6];
  const float* b_f    = (const float*)d_in[7];
  const float* W_out  = (const float*)d_in[8];
  const float* b_out  = (const float*)d_in[9];
  float* out = (float*)d_out;

  char* ws = (char*)d_ws;
  ushort* wout_bf = (ushort*)(ws + 0);          // 65,536,000
  ushort* in_hi   = (ushort*)(ws + 65536000);   // cast targets (dead after split-gemm)
  ushort* in_lo   = (ushort*)(ws + 73924608);
  ushort* wx_hi   = (ushort*)(ws + 82313216);
  ushort* wx_lo   = (ushort*)(ws + 86507520);
  ushort* wc_hi   = (ushort*)(ws + 90701824);
  ushort* wc_lo   = (ushort*)(ws + 94896128);
  unsigned* slots = (unsigned*)(ws + 107479040);
  ushort* cinit   = (ushort*)(ws + 107479296);  // chunked init c-hi (64 KB)
  // overlays (regions dead at time of use):
  ushort* cstate  = in_hi;                      // [T][CSTEP] chunked c-hi, 8,388,608 B
  float*  pmax    = (float*)in_lo;              // [4096][250] (after split-gemm)
  float*  psum    = (float*)(ws + 78020608);
  float*  lse     = (float*)wx_hi;              // [4096]
  float*  ixfx    = out;                        // [4096][2048] scratch in logits region

  cast_bf16_kernel <<<2048,256,0,stream>>>(W_out, wout_bf, V_DIM*H_DIM/4);
  cast_split_kernel<<<1024,256,0,stream>>>(input, in_hi, in_lo, MROWS*H_DIM/4);
  cast_split_kernel<<<256,256,0,stream>>>(w_ix, wx_hi,             wx_lo,             H_DIM*H_DIM/4);
  cast_split_kernel<<<256,256,0,stream>>>(w_fx, wx_hi+H_DIM*H_DIM, wx_lo+H_DIM*H_DIM, H_DIM*H_DIM/4);
  cast_split_kernel<<<256,256,0,stream>>>(w_ic, wc_hi,             wc_lo,             H_DIM*H_DIM/4);
  cast_split_kernel<<<256,256,0,stream>>>(w_fc, wc_hi+H_DIM*H_DIM, wc_lo+H_DIM*H_DIM, H_DIM*H_DIM/4);

  // ixfx = input @ [w_ix; w_fx]^T (split-bf16, fused)
  gemm_bt_split<<<32*16,256,0,stream>>>(in_hi, in_lo, wx_hi, wx_lo, ixfx, 2048, H_DIM, 16);

  init_c_kernel<<<128,256,0,stream>>>(hidden, cinit, slots);

  ran_all<<<NBLK,512,0,stream>>>(cinit, cstate, hidden, wc_hi, wc_lo, b_i, b_f,
                                 ixfx, input, out + (size_t)MROWS*V_DIM, slots);

  // logits + fused LSE partials; A staged directly from chunked c-state
  gemm_bt<<<32*250,256,0,stream>>>(cstate, wout_bf, out, b_out, V_DIM, H_DIM, 250, 1, 1, pmax, psum);
  lse_reduce<<<MROWS,64,0,stream>>>(pmax, psum, lse, 250);
  sub_kernel<<<MROWS,256,0,stream>>>(out, lse);
}

// Round 10
// 1998.822 us; speedup vs baseline: 1.0264x; 1.0191x over previous
//
#include <hip/hip_runtime.h>

typedef __attribute__((ext_vector_type(4))) float f32x4;
typedef __attribute__((ext_vector_type(8))) short bf16x8;
typedef __attribute__((ext_vector_type(4))) unsigned u32x4;

#define T_DIM 128
#define B_DIM 32
#define H_DIM 1024
#define V_DIM 32000
#define MROWS 4096    // T*B
#define NBLK 64       // persistent recurrence blocks
#define CSTEP 32768   // ushorts per t in untagged c-state: 64 chunks x (32m x 16k)
#define PUBSTEP 32768 // dwords per slot in tagged pub buffer
#define WSTRIDE 1028  // LDS W row stride (ushorts): bank step 2 -> conflict-free

__device__ __forceinline__ ushort f2bf(float f){
  union { float f; unsigned u; } x; x.f = f;
  unsigned u = x.u;
  unsigned r = (u + 0x7fffu + ((u >> 16) & 1u)) >> 16;
  return (ushort)r;
}
__device__ __forceinline__ float bf2f(ushort h){
  union { unsigned u; float f; } x; x.u = ((unsigned)h) << 16;
  return x.f;
}

__device__ __forceinline__ void async_copy16(void* lds, const void* g){
  __builtin_amdgcn_global_load_lds((const __attribute__((address_space(1))) void*)g,
                                   (__attribute__((address_space(3))) void*)lds, 16, 0, 0);
}

// ---------------- casts ----------------
__global__ void cast_bf16_kernel(const float* __restrict__ s, ushort* __restrict__ d, int n4){
  int stride = gridDim.x * blockDim.x;
  for (int i = blockIdx.x*blockDim.x + threadIdx.x; i < n4; i += stride){
    float4 v = ((const float4*)s)[i];
    ushort4 o = make_ushort4(f2bf(v.x), f2bf(v.y), f2bf(v.z), f2bf(v.w));
    ((ushort4*)d)[i] = o;
  }
}

__global__ void cast_split_kernel(const float* __restrict__ s, ushort* __restrict__ dh,
                                  ushort* __restrict__ dl, int n4){
  int stride = gridDim.x * blockDim.x;
  for (int i = blockIdx.x*blockDim.x + threadIdx.x; i < n4; i += stride){
    float4 v = ((const float4*)s)[i];
    ushort4 h = make_ushort4(f2bf(v.x), f2bf(v.y), f2bf(v.z), f2bf(v.w));
    ushort4 l = make_ushort4(f2bf(v.x - bf2f(h.x)), f2bf(v.y - bf2f(h.y)),
                             f2bf(v.z - bf2f(h.z)), f2bf(v.w - bf2f(h.w)));
    ((ushort4*)dh)[i] = h;
    ((ushort4*)dl)[i] = l;
  }
}

// ---------------- m97-style bf16 GEMM + optional fused LSE partials ----------------
// C[M][N] = A[M][K]*B[N][K]^T + bias. order==1: XCD-banded (gridDim%8==0, 32 M-tiles).
// achunk==1: A in chunked c-state layout [t][k>>4][m][k&15] (t=row>>5, m=row&31).
__global__ __launch_bounds__(256) void gemm_bt(
    const ushort* __restrict__ A, const ushort* __restrict__ B,
    float* __restrict__ C, const float* __restrict__ bias,
    int N, int K, int NTN, int order, int achunk,
    float* __restrict__ pmax, float* __restrict__ psum)
{
  __shared__ ushort lA[128*32];
  __shared__ ushort lB[128*32];
  __shared__ float pmS[4][64], psS[4][64];
  int tid = threadIdx.x;
  int lane = tid & 63, wid = tid >> 6;
  int bid = blockIdx.x;
  int tm, tn;
  if (order){
    int xcd = bid & 7, id = bid >> 3;
    tn = id >> 2;                 // B tile fetched once per XCD
    tm = (xcd << 2) | (id & 3);   // 4-tm A band resident per XCD L2
  } else {
    tm = bid / NTN; tn = bid % NTN;
  }
  int row0 = tm << 7, col0 = tn << 7;

  f32x4 acc[4][4] = {};

  auto stage = [&](const ushort* __restrict__ g, ushort* l, int r0, int k0){
    int c = wid << 1;
    const ushort* s0 = g + (size_t)(r0 + (c<<4) + (lane>>2))*K + k0 + ((lane&3)<<3);
    async_copy16(l + (c<<9), s0);
    async_copy16(l + ((c+1)<<9), s0 + (size_t)16*K);
  };
  auto stageAc = [&](const ushort* __restrict__ g, ushort* l, int r0, int k0){
    int c = wid << 1;
    int cb  = (k0 >> 4) + ((lane & 3) >> 1);
    int sub = (lane & 1) << 3;
    int rA = r0 + (c<<4) + (lane>>2);
    const ushort* sA = g + ((size_t)(rA>>5)<<15) + (cb<<9) + ((rA&31)<<4) + sub;
    async_copy16(l + (c<<9), sA);
    int rB = rA + 16;
    const ushort* sB = g + ((size_t)(rB>>5)<<15) + (cb<<9) + ((rB&31)<<4) + sub;
    async_copy16(l + ((c+1)<<9), sB);
  };

  int nk = K >> 5;
  if (achunk) stageAc(A, lA, row0, 0); else stage(A, lA, row0, 0);
  stage(B, lB, col0, 0);
  int wm = (wid >> 1) << 6, wn = (wid & 1) << 6;
  int kg = (lane >> 4) << 3;
  int ar = lane & 15;

  for (int kt = 0; kt < nk; ++kt){
    __syncthreads();
    bf16x8 af[4], bfr[4];
    #pragma unroll
    for (int mi = 0; mi < 4; ++mi) af[mi]  = *(const bf16x8*)&lA[(wm + mi*16 + ar)*32 + kg];
    #pragma unroll
    for (int ni = 0; ni < 4; ++ni) bfr[ni] = *(const bf16x8*)&lB[(wn + ni*16 + ar)*32 + kg];
    #pragma unroll
    for (int mi = 0; mi < 4; ++mi)
      #pragma unroll
      for (int ni = 0; ni < 4; ++ni)
        acc[mi][ni] = __builtin_amdgcn_mfma_f32_16x16x32_bf16(af[mi], bfr[ni], acc[mi][ni], 0, 0, 0);
    if (kt + 1 < nk){
      __syncthreads();
      if (achunk) stageAc(A, lA, row0, (kt+1) << 5); else stage(A, lA, row0, (kt+1) << 5);
      stage(B, lB, col0, (kt+1) << 5);
    }
  }

  int rr = (lane >> 4) << 2;
  float bb4[4];
  #pragma unroll
  for (int ni = 0; ni < 4; ++ni) bb4[ni] = bias ? bias[col0 + wn + ni*16 + ar] : 0.f;

  #pragma unroll
  for (int mi = 0; mi < 4; ++mi){
    #pragma unroll
    for (int q = 0; q < 4; ++q){
      int r = row0 + wm + mi*16 + rr + q;
      float vals[4];
      #pragma unroll
      for (int ni = 0; ni < 4; ++ni){
        vals[ni] = acc[mi][ni][q] + bb4[ni];
        C[(size_t)r * N + col0 + wn + ni*16 + ar] = vals[ni];
      }
      if (pmax){
        float m = fmaxf(fmaxf(vals[0], vals[1]), fmaxf(vals[2], vals[3]));
        #pragma unroll
        for (int o = 1; o < 16; o <<= 1) m = fmaxf(m, __shfl_xor(m, o));
        float s = expf(vals[0]-m) + expf(vals[1]-m) + expf(vals[2]-m) + expf(vals[3]-m);
        #pragma unroll
        for (int o = 1; o < 16; o <<= 1) s += __shfl_xor(s, o);
        if (ar == 0){ int rl = mi*16 + rr + q; pmS[wid][rl] = m; psS[wid][rl] = s; }
      }
    }
  }
  if (pmax){
    __syncthreads();
    if (tid < 128){
      int rl = tid & 63, half = tid >> 6;
      int w0 = half*2, w1 = w0 + 1;
      float m0 = pmS[w0][rl], m1 = pmS[w1][rl];
      float s0 = psS[w0][rl], s1 = psS[w1][rl];
      float M = fmaxf(m0, m1);
      float S = s0*expf(m0-M) + s1*expf(m1-M);
      int r = row0 + half*64 + rl;
      pmax[(size_t)r*NTN + tn] = M;
      psum[(size_t)r*NTN + tn] = S;
    }
  }
}

// ---------------- fused split-bf16 GEMM: C = Ah*Bh^T + Ah*Bl^T + Al*Bh^T ----------------
__global__ __launch_bounds__(256) void gemm_bt_split(
    const ushort* __restrict__ Ah, const ushort* __restrict__ Al,
    const ushort* __restrict__ Bh, const ushort* __restrict__ Bl,
    float* __restrict__ C, int N, int K, int NTN)
{
  __shared__ ushort lAh[128*32], lAl[128*32], lBh[128*32], lBl[128*32];
  int tid = threadIdx.x;
  int lane = tid & 63, wid = tid >> 6;
  int tm = blockIdx.x / NTN, tn = blockIdx.x % NTN;
  int row0 = tm << 7, col0 = tn << 7;

  f32x4 acc[4][4] = {};

  auto stage = [&](const ushort* __restrict__ g, ushort* l, int r0, int k0){
    int c = wid << 1;
    const ushort* s0 = g + (size_t)(r0 + (c<<4) + (lane>>2))*K + k0 + ((lane&3)<<3);
    async_copy16(l + (c<<9), s0);
    async_copy16(l + ((c+1)<<9), s0 + (size_t)16*K);
  };

  int nk = K >> 5;
  stage(Ah, lAh, row0, 0); stage(Al, lAl, row0, 0);
  stage(Bh, lBh, col0, 0); stage(Bl, lBl, col0, 0);
  int wm = (wid >> 1) << 6, wn = (wid & 1) << 6;
  int kg = (lane >> 4) << 3;
  int ar = lane & 15;

  for (int kt = 0; kt < nk; ++kt){
    __syncthreads();
    bf16x8 afh[4], afl[4], bfh[4], bfl[4];
    #pragma unroll
    for (int mi = 0; mi < 4; ++mi){
      afh[mi] = *(const bf16x8*)&lAh[(wm + mi*16 + ar)*32 + kg];
      afl[mi] = *(const bf16x8*)&lAl[(wm + mi*16 + ar)*32 + kg];
    }
    #pragma unroll
    for (int ni = 0; ni < 4; ++ni){
      bfh[ni] = *(const bf16x8*)&lBh[(wn + ni*16 + ar)*32 + kg];
      bfl[ni] = *(const bf16x8*)&lBl[(wn + ni*16 + ar)*32 + kg];
    }
    #pragma unroll
    for (int mi = 0; mi < 4; ++mi)
      #pragma unroll
      for (int ni = 0; ni < 4; ++ni){
        acc[mi][ni] = __builtin_amdgcn_mfma_f32_16x16x32_bf16(afh[mi], bfh[ni], acc[mi][ni], 0, 0, 0);
        acc[mi][ni] = __builtin_amdgcn_mfma_f32_16x16x32_bf16(afh[mi], bfl[ni], acc[mi][ni], 0, 0, 0);
        acc[mi][ni] = __builtin_amdgcn_mfma_f32_16x16x32_bf16(afl[mi], bfh[ni], acc[mi][ni], 0, 0, 0);
      }
    if (kt + 1 < nk){
      __syncthreads();
      stage(Ah, lAh, row0, (kt+1) << 5); stage(Al, lAl, row0, (kt+1) << 5);
      stage(Bh, lBh, col0, (kt+1) << 5); stage(Bl, lBl, col0, (kt+1) << 5);
    }
  }

  int rr = (lane >> 4) << 2;
  #pragma unroll
  for (int mi = 0; mi < 4; ++mi)
    #pragma unroll
    for (int ni = 0; ni < 4; ++ni){
      int r  = row0 + wm + mi*16 + rr;
      int cc = col0 + wn + ni*16 + ar;
      #pragma unroll
      for (int q = 0; q < 4; ++q)
        C[(size_t)(r + q) * N + cc] = acc[mi][ni][q];
    }
}

// ---------------- persistent recurrence v9: tagged dataflow, no barrier ----------------
// pub[slot s] holds c_s as dwords (tag=s+1)<<16 | bf16. One atomic dword carries data+flag:
// producers publish with plain sc1 write-through stores (no drain, no signal); consumers
// retry-load their A-frags L3-direct (sc0 sc1) until all tags match. r7 compute structure.
__global__ __launch_bounds__(512) void ran_all(
    unsigned* __restrict__ pub, const float* __restrict__ hiddenf,
    const ushort* __restrict__ wh, const ushort* __restrict__ wl,
    const float* __restrict__ b_i, const float* __restrict__ b_f,
    const float* __restrict__ ixfx, const float* __restrict__ x_all,
    float* __restrict__ hid_final)
{
  __shared__ ushort lWh[32*WSTRIDE];
  __shared__ ushort lWl[32*WSTRIDE];
  __shared__ f32x4 part[4][2][2][64];   // [kq][mh][gate][lane]
  __shared__ float gsm[2*32*17];
  __shared__ float cfl[32][17];

  int tid = threadIdx.x, lane = tid & 63, wid = tid >> 6;
  int kq = wid & 3, mh = wid >> 2;           // MFMA roles
  int rgate = wid & 1, rmh = (wid >> 1) & 1; // reduce roles (wid<4)
  int bid = blockIdx.x;
  int nb = bid << 4;
  int ar = lane & 15, kg = (lane >> 4) << 3;
  int um = tid >> 4, uk = tid & 15;

  #pragma unroll
  for (int u = 0; u < 8; ++u){
    int unit = u*512 + tid;
    int r = unit >> 7, off = (unit & 127) << 3;
    int g = r >> 4, c = r & 15;
    size_t gsrc = (size_t)((g<<10) + nb + c) * H_DIM + off;
    *(bf16x8*)&lWh[r*WSTRIDE + off] = *(const bf16x8*)&wh[gsrc];
    *(bf16x8*)&lWl[r*WSTRIDE + off] = *(const bf16x8*)&wl[gsrc];
  }
  cfl[um][uk] = hiddenf[(um<<10) + nb + uk];
  float bb = (rgate ? b_f : b_i)[nb + ar];
  const ushort* b0h = &lWh[(     ar)*WSTRIDE + (kq<<8) + kg];
  const ushort* b0l = &lWl[(     ar)*WSTRIDE + (kq<<8) + kg];
  const ushort* b1h = &lWh[(16 + ar)*WSTRIDE + (kq<<8) + kg];
  const ushort* b1l = &lWl[(16 + ar)*WSTRIDE + (kq<<8) + kg];
  // A-frag base in dwords within a slot: chunk*512 + m*16 + k
  int abase = (kq<<13) + ((kg>>4)<<9) + (((mh<<4) + ar)<<4) + (kg & 8);
  __syncthreads();

  for (int t = 0; t < T_DIM; ++t){
    // per-step x/ixfx loads (issued early; latency hides under tag-wait)
    float xq1 = x_all[((size_t)t<<15) + (um<<10) + nb + uk];
    float pix[4];
    if (wid < 4){
      const float* ix_t = ixfx + ((size_t)t<<16);
      #pragma unroll
      for (int q = 0; q < 4; ++q){
        int m = (rmh<<4) + ((lane>>4)<<2) + q;
        pix[q] = ix_t[m*2048 + (rgate<<10) + nb + ar];
      }
    }

    // dataflow read of c_t (slot t, expected tag t+1): 8 frags x 8 tagged dwords
    const unsigned* ps = pub + ((size_t)t << 15) + abase;
    unsigned expt = (unsigned)(t + 1) << 16;
    u32x4 w0[8], w1[8];
    int tries = 0;
    while (1){
      #pragma unroll
      for (int f = 0; f < 8; ++f){
        const unsigned* p = ps + (f << 10);
        asm volatile("global_load_dwordx4 %0, %2, off sc0 sc1\n\t"
                     "global_load_dwordx4 %1, %2, off offset:16 sc0 sc1"
                     : "=&v"(w0[f]), "=&v"(w1[f]) : "v"(p));
      }
      asm volatile("s_waitcnt vmcnt(0)" ::: "memory");
      __builtin_amdgcn_sched_barrier(0);
      unsigned bad = 0;
      #pragma unroll
      for (int f = 0; f < 8; ++f){
        bad |= (w0[f][0]^expt)|(w0[f][1]^expt)|(w0[f][2]^expt)|(w0[f][3]^expt)
             | (w1[f][0]^expt)|(w1[f][1]^expt)|(w1[f][2]^expt)|(w1[f][3]^expt);
      }
      if (__ballot((bad & 0xFFFF0000u) != 0) == 0ull) break;
      if (++tries > (1<<15)) break;   // bounded: fail fast, not hang
    }

    f32x4 g0h = {}, g0l = {}, g1h = {}, g1l = {};
    #pragma unroll
    for (int f = 0; f < 8; ++f){
      union { unsigned u[4]; bf16x8 v; } cv;
      cv.u[0] = (w0[f][0] & 0xFFFFu) | (w0[f][1] << 16);
      cv.u[1] = (w0[f][2] & 0xFFFFu) | (w0[f][3] << 16);
      cv.u[2] = (w1[f][0] & 0xFFFFu) | (w1[f][1] << 16);
      cv.u[3] = (w1[f][2] & 0xFFFFu) | (w1[f][3] << 16);
      int ob = f << 5;
      bf16x8 v0h = *(const bf16x8*)&b0h[ob];
      bf16x8 v0l = *(const bf16x8*)&b0l[ob];
      bf16x8 v1h = *(const bf16x8*)&b1h[ob];
      bf16x8 v1l = *(const bf16x8*)&b1l[ob];
      g0h = __builtin_amdgcn_mfma_f32_16x16x32_bf16(cv.v, v0h, g0h, 0, 0, 0);
      g0l = __builtin_amdgcn_mfma_f32_16x16x32_bf16(cv.v, v0l, g0l, 0, 0, 0);
      g1h = __builtin_amdgcn_mfma_f32_16x16x32_bf16(cv.v, v1h, g1h, 0, 0, 0);
      g1l = __builtin_amdgcn_mfma_f32_16x16x32_bf16(cv.v, v1l, g1l, 0, 0, 0);
    }
    part[kq][mh][0][lane] = g0h + g0l;
    part[kq][mh][1][lane] = g1h + g1l;
    __syncthreads();

    if (wid < 4){
      f32x4 sum = part[0][rmh][rgate][lane] + part[1][rmh][rgate][lane]
                + part[2][rmh][rgate][lane] + part[3][rmh][rgate][lane];
      #pragma unroll
      for (int q = 0; q < 4; ++q){
        int m = (rmh<<4) + ((lane>>4)<<2) + q;
        float pre = sum[q] + bb + pix[q];
        gsm[((rgate<<5) + m)*17 + ar] = 1.f / (1.f + expf(-pre));
      }
    }
    __syncthreads();

    {
      float iv = gsm[um*17 + uk];
      float fv = gsm[(32+um)*17 + uk];
      float cv2 = cfl[um][uk];
      float cn = iv * xq1 + fv * cv2;
      cfl[um][uk] = cn;
      unsigned word = ((unsigned)(t + 2) << 16) | (unsigned)f2bf(cn);
      // tag+data in one dword; sc1 write-through; NO drain, NO signal
      __hip_atomic_store(&pub[((size_t)(t+1) << 15) + (bid << 9) + tid], word,
                         __ATOMIC_RELAXED, __HIP_MEMORY_SCOPE_AGENT);
      if (t == T_DIM-1) hid_final[(um<<10) + nb + uk] = cn;
    }
    __syncthreads();
  }
}

// init: write tagged c_init into pub slot 0 (tag = 1)
__global__ void init_c_kernel(const float* __restrict__ hidden, unsigned* __restrict__ pub){
  int i = blockIdx.x * blockDim.x + threadIdx.x;   // 0..32767
  float v = hidden[i];
  int m = i >> 10, col = i & 1023;
  pub[((col>>4)<<9) + (m<<4) + (col&15)] = (1u << 16) | (unsigned)f2bf(v);
}

// untag: pub slots 1..128 -> cstate [t][chunk][m][k] bf16 (for the Vproj GEMM)
__global__ void untag_kernel(const unsigned* __restrict__ pub, ushort* __restrict__ cst){
  int e = (blockIdx.x * blockDim.x + threadIdx.x) << 2;  // 4 elems/thread
  int s = e >> 15, w = e & 32767;
  const unsigned* p = pub + ((size_t)(s + 1) << 15) + w;
  ushort4 o = make_ushort4((ushort)p[0], (ushort)p[1], (ushort)p[2], (ushort)p[3]);
  *(ushort4*)&cst[e] = o;
}

// ---------------- lse reduce + subtract ----------------
__global__ __launch_bounds__(64) void lse_reduce(const float* __restrict__ pmax,
                                                 const float* __restrict__ psum,
                                                 float* __restrict__ lse, int ntn){
  int row = blockIdx.x, lane = threadIdx.x;
  float m = -1e30f, s = 0.f;
  for (int i = lane; i < ntn; i += 64){
    float mi = pmax[(size_t)row*ntn + i], si = psum[(size_t)row*ntn + i];
    float M = fmaxf(m, mi);
    s = s*expf(m - M) + si*expf(mi - M);
    m = M;
  }
  #pragma unroll
  for (int o = 32; o; o >>= 1){
    float m2 = __shfl_xor(m, o), s2 = __shfl_xor(s, o);
    float M = fmaxf(m, m2);
    s = s*expf(m - M) + s2*expf(m2 - M);
    m = M;
  }
  if (lane == 0) lse[row] = m + logf(s);
}

__global__ __launch_bounds__(256) void sub_kernel(float* __restrict__ logits,
                                                  const float* __restrict__ lse){
  size_t row = blockIdx.x;
  float l = lse[row];
  float4* p4 = (float4*)(logits + row * (size_t)V_DIM);
  for (int i = threadIdx.x; i < V_DIM/4; i += 256){
    float4 v = p4[i];
    v.x -= l; v.y -= l; v.z -= l; v.w -= l;
    p4[i] = v;
  }
}

// ---------------- launch ----------------
extern "C" void kernel_launch(void* const* d_in, const int* in_sizes, int n_in,
                              void* d_out, int out_size, void* d_ws, size_t ws_size,
                              hipStream_t stream)
{
  const float* input  = (const float*)d_in[0];
  const float* hidden = (const float*)d_in[1];
  const float* w_ic   = (const float*)d_in[2];
  const float* w_ix   = (const float*)d_in[3];
  const float* w_fc   = (const float*)d_in[4];
  const float* w_fx   = (const float*)d_in[5];
  const float* b_i    = (const float*)d_in[6];
  const float* b_f    = (const float*)d_in[7];
  const float* W_out  = (const float*)d_in[8];
  const float* b_out  = (const float*)d_in[9];
  float* out = (float*)d_out;

  char* ws = (char*)d_ws;
  ushort* wout_bf = (ushort*)(ws + 0);          // 0 .. 65,536,000
  ushort* in_hi   = (ushort*)(ws + 65536000);   // cast targets (dead after split-gemm)
  ushort* in_lo   = (ushort*)(ws + 73924608);
  ushort* wx_hi   = (ushort*)(ws + 82313216);   // dead after split-gemm
  ushort* wx_lo   = (ushort*)(ws + 86507520);
  ushort* wc_hi   = (ushort*)(ws + 90701824);   // dead after ran_all
  ushort* wc_lo   = (ushort*)(ws + 94896128);
  // overlays (regions dead at time of use):
  unsigned* pub   = (unsigned*)(ws + 65536000); // [129][32768] tagged c, 16,908,288 B (over in_hi/in_lo/+131KB wx_hi)
  ushort* cstate  = (ushort*)(ws + 82444288);   // [128][32768] bf16, 8,388,608 B (over wx tail + 131KB wc_hi; written post-ran_all)
  float*  pmax    = (float*)(ws + 94896128);    // over wc_lo (dead post-ran_all), 4,096,000 B
  float*  psum    = (float*)(ws + 99090432);    // 4,096,000 B
  float*  lse     = (float*)(ws + 103186432);   // 16 KB
  float*  ixfx    = out;                        // [4096][2048] scratch in logits region

  cast_bf16_kernel <<<2048,256,0,stream>>>(W_out, wout_bf, V_DIM*H_DIM/4);
  cast_split_kernel<<<1024,256,0,stream>>>(input, in_hi, in_lo, MROWS*H_DIM/4);
  cast_split_kernel<<<256,256,0,stream>>>(w_ix, wx_hi,             wx_lo,             H_DIM*H_DIM/4);
  cast_split_kernel<<<256,256,0,stream>>>(w_fx, wx_hi+H_DIM*H_DIM, wx_lo+H_DIM*H_DIM, H_DIM*H_DIM/4);
  cast_split_kernel<<<256,256,0,stream>>>(w_ic, wc_hi,             wc_lo,             H_DIM*H_DIM/4);
  cast_split_kernel<<<256,256,0,stream>>>(w_fc, wc_hi+H_DIM*H_DIM, wc_lo+H_DIM*H_DIM, H_DIM*H_DIM/4);

  // ixfx = input @ [w_ix; w_fx]^T (split-bf16, fused) — uses in_hi/in_lo/wx before overlay
  gemm_bt_split<<<32*16,256,0,stream>>>(in_hi, in_lo, wx_hi, wx_lo, ixfx, 2048, H_DIM, 16);

  // clear tags (graph-replay safety), seed slot 0
  hipMemsetAsync(pub, 0, (size_t)129 * PUBSTEP * 4, stream);
  init_c_kernel<<<128,256,0,stream>>>(hidden, pub);

  ran_all<<<NBLK,512,0,stream>>>(pub, hidden, wc_hi, wc_lo, b_i, b_f,
                                 ixfx, input, out + (size_t)MROWS*V_DIM);

  // pub -> cstate (bf16), then logits + fused LSE partials
  untag_kernel<<<4096,256,0,stream>>>(pub, cstate);
  gemm_bt<<<32*250,256,0,stream>>>(cstate, wout_bf, out, b_out, V_DIM, H_DIM, 250, 1, 1, pmax, psum);
  lse_reduce<<<MROWS,64,0,stream>>>(pmax, psum, lse, 250);
  sub_kernel<<<MROWS,256,0,stream>>>(out, lse);
}

// Round 11
// 1914.661 us; speedup vs baseline: 1.0716x; 1.0440x over previous
//
#include <hip/hip_runtime.h>

typedef __attribute__((ext_vector_type(4))) float f32x4;
typedef __attribute__((ext_vector_type(8))) short bf16x8;
typedef __attribute__((ext_vector_type(4))) unsigned u32x4;

#define T_DIM 128
#define B_DIM 32
#define H_DIM 1024
#define V_DIM 32000
#define MROWS 4096    // T*B
#define NBLK 64       // persistent recurrence blocks
#define PUBSTEP 32768 // dwords per slot in tagged pub buffer
#define WSTRIDE 1028  // LDS W row stride (ushorts): bank step 2 -> conflict-free

__device__ __forceinline__ ushort f2bf(float f){
  union { float f; unsigned u; } x; x.f = f;
  unsigned u = x.u;
  unsigned r = (u + 0x7fffu + ((u >> 16) & 1u)) >> 16;
  return (ushort)r;
}
__device__ __forceinline__ float bf2f(ushort h){
  union { unsigned u; float f; } x; x.u = ((unsigned)h) << 16;
  return x.f;
}

__device__ __forceinline__ void async_copy16(void* lds, const void* g){
  __builtin_amdgcn_global_load_lds((const __attribute__((address_space(1))) void*)g,
                                   (__attribute__((address_space(3))) void*)lds, 16, 0, 0);
}

// ---------------- casts ----------------
__global__ void cast_bf16_kernel(const float* __restrict__ s, ushort* __restrict__ d, int n4){
  int stride = gridDim.x * blockDim.x;
  for (int i = blockIdx.x*blockDim.x + threadIdx.x; i < n4; i += stride){
    float4 v = ((const float4*)s)[i];
    ushort4 o = make_ushort4(f2bf(v.x), f2bf(v.y), f2bf(v.z), f2bf(v.w));
    ((ushort4*)d)[i] = o;
  }
}

__global__ void cast_split_kernel(const float* __restrict__ s, ushort* __restrict__ dh,
                                  ushort* __restrict__ dl, int n4){
  int stride = gridDim.x * blockDim.x;
  for (int i = blockIdx.x*blockDim.x + threadIdx.x; i < n4; i += stride){
    float4 v = ((const float4*)s)[i];
    ushort4 h = make_ushort4(f2bf(v.x), f2bf(v.y), f2bf(v.z), f2bf(v.w));
    ushort4 l = make_ushort4(f2bf(v.x - bf2f(h.x)), f2bf(v.y - bf2f(h.y)),
                             f2bf(v.z - bf2f(h.z)), f2bf(v.w - bf2f(h.w)));
    ((ushort4*)dh)[i] = h;
    ((ushort4*)dl)[i] = l;
  }
}

// ---------------- Vproj: 256x256-tile, BK=64, counted-vmcnt double-buffer ----------------
// C[4096][32000] = A(cstate chunked)[4096][1024] * B[32000][1024]^T + bias, fused LSE partials.
// A chunked: row r -> t=r>>5, m=r&31; addr = t*32768 + (k>>4)*512 + m*16 + (k&15).
// LDS linear [256][64] per tile; XOR-granule swizzle: conceptual granule c of row r stored at
// physical granule c^(r&7) (pre-swizzled global source, swizzled ds_read) -> 2-way conflicts.
__global__ __launch_bounds__(512) void gemm256(
    const ushort* __restrict__ A, const ushort* __restrict__ B,
    float* __restrict__ C, const float* __restrict__ bias,
    float* __restrict__ pmax, float* __restrict__ psum)
{
  __shared__ ushort lA[2][256*64];
  __shared__ ushort lB[2][256*64];
  __shared__ float redm[2][4][128], reds[2][4][128];

  const int K = 1024, N = V_DIM, NTN = 125, NT = 16;
  int tid = threadIdx.x, lane = tid & 63, wid = tid >> 6;
  int wm = wid >> 2, wn = wid & 3;
  int bid = blockIdx.x;
  int xcd = bid & 7, id = bid >> 3;       // 2000 blocks: 250 per XCD
  int tm = (xcd << 1) | (id & 1);         // 2 M-bands per XCD (A band L2-resident)
  int tn = id >> 1;                       // 125 N-tiles
  int row0 = tm << 8, col0 = tn << 8;
  int ar = lane & 15, kg = (lane >> 4) << 3;

  // stage one K-tile (A 32KB + B 32KB): 4+4 gload_lds16 per thread, linear LDS dst,
  // swizzled global source (conceptual granule g^(row&7) lands at physical granule g)
  auto STAGE = [&](int buf, int k0){
    #pragma unroll
    for (int j = 0; j < 4; ++j){
      int l16 = j*512 + tid;
      int row = l16 >> 3, g = l16 & 7;
      int kc = (g ^ (row & 7)) << 3;        // source conceptual k-offset
      int rA = row0 + row, k = k0 + kc;
      const ushort* sA = A + ((size_t)(rA>>5)<<15) + ((k>>4)<<9) + ((rA&31)<<4) + (k&15);
      async_copy16(&lA[buf][l16<<3], sA);
    }
    #pragma unroll
    for (int j = 0; j < 4; ++j){
      int l16 = j*512 + tid;
      int row = l16 >> 3, g = l16 & 7;
      int kc = (g ^ (row & 7)) << 3;
      const ushort* sB = B + (size_t)(col0 + row)*K + k0 + kc;
      async_copy16(&lB[buf][l16<<3], sB);
    }
  };

  f32x4 acc[8][4] = {};

  STAGE(0, 0);
  for (int t = 0; t < NT; ++t){
    if (t + 1 < NT) STAGE((t+1) & 1, (t+1) << 6);
    if (t + 1 < NT) asm volatile("s_waitcnt vmcnt(8)" ::: "memory");
    else            asm volatile("s_waitcnt vmcnt(0)" ::: "memory");
    __builtin_amdgcn_s_barrier();
    __builtin_amdgcn_sched_barrier(0);
    const ushort* bufA = lA[t & 1];
    const ushort* bufB = lB[t & 1];
    #pragma unroll
    for (int ks = 0; ks < 2; ++ks){
      bf16x8 a[8], b[4];
      #pragma unroll
      for (int fr = 0; fr < 8; ++fr){
        int row = wm*128 + fr*16 + ar;
        int gk = ks*4 + (kg >> 3);
        a[fr] = *(const bf16x8*)&bufA[row*64 + ((gk ^ (row & 7)) << 3)];
      }
      #pragma unroll
      for (int fc = 0; fc < 4; ++fc){
        int row = wn*64 + fc*16 + ar;
        int gk = ks*4 + (kg >> 3);
        b[fc] = *(const bf16x8*)&bufB[row*64 + ((gk ^ (row & 7)) << 3)];
      }
      __builtin_amdgcn_s_setprio(1);
      #pragma unroll
      for (int fr = 0; fr < 8; ++fr)
        #pragma unroll
        for (int fc = 0; fc < 4; ++fc)
          acc[fr][fc] = __builtin_amdgcn_mfma_f32_16x16x32_bf16(a[fr], b[fc], acc[fr][fc], 0, 0, 0);
      __builtin_amdgcn_s_setprio(0);
    }
    __builtin_amdgcn_sched_barrier(0);
    __builtin_amdgcn_s_barrier();      // all waves done reading buf[t&1] before restage
    __builtin_amdgcn_sched_barrier(0);
  }

  // epilogue: bias + C-write + per-(row, tile) LSE partials
  float bb4[4];
  #pragma unroll
  for (int fc = 0; fc < 4; ++fc) bb4[fc] = bias[col0 + wn*64 + fc*16 + ar];
  #pragma unroll
  for (int fr = 0; fr < 8; ++fr){
    #pragma unroll
    for (int q = 0; q < 4; ++q){
      int rl = fr*16 + (lane>>4)*4 + q;          // row within wave's 128
      int r = row0 + wm*128 + rl;
      float vals[4];
      #pragma unroll
      for (int fc = 0; fc < 4; ++fc){
        vals[fc] = acc[fr][fc][q] + bb4[fc];
        C[(size_t)r * N + col0 + wn*64 + fc*16 + ar] = vals[fc];
      }
      float m = fmaxf(fmaxf(vals[0], vals[1]), fmaxf(vals[2], vals[3]));
      #pragma unroll
      for (int o = 1; o < 16; o <<= 1) m = fmaxf(m, __shfl_xor(m, o));
      float s = expf(vals[0]-m) + expf(vals[1]-m) + expf(vals[2]-m) + expf(vals[3]-m);
      #pragma unroll
      for (int o = 1; o < 16; o <<= 1) s += __shfl_xor(s, o);
      if (ar == 0){ redm[wm][wn][rl] = m; reds[wm][wn][rl] = s; }
    }
  }
  __syncthreads();
  if (tid < 256){
    int wm2 = tid >> 7, rl = tid & 127;
    float m0 = redm[wm2][0][rl], m1 = redm[wm2][1][rl];
    float m2 = redm[wm2][2][rl], m3 = redm[wm2][3][rl];
    float M = fmaxf(fmaxf(m0, m1), fmaxf(m2, m3));
    float S = reds[wm2][0][rl]*expf(m0-M) + reds[wm2][1][rl]*expf(m1-M)
            + reds[wm2][2][rl]*expf(m2-M) + reds[wm2][3][rl]*expf(m3-M);
    int r = row0 + wm2*128 + rl;
    pmax[(size_t)r*NTN + tn] = M;
    psum[(size_t)r*NTN + tn] = S;
  }
}

// ---------------- fused split-bf16 GEMM: C = Ah*Bh^T + Ah*Bl^T + Al*Bh^T ----------------
__global__ __launch_bounds__(256) void gemm_bt_split(
    const ushort* __restrict__ Ah, const ushort* __restrict__ Al,
    const ushort* __restrict__ Bh, const ushort* __restrict__ Bl,
    float* __restrict__ C, int N, int K, int NTN)
{
  __shared__ ushort lAh[128*32], lAl[128*32], lBh[128*32], lBl[128*32];
  int tid = threadIdx.x;
  int lane = tid & 63, wid = tid >> 6;
  int tm = blockIdx.x / NTN, tn = blockIdx.x % NTN;
  int row0 = tm << 7, col0 = tn << 7;

  f32x4 acc[4][4] = {};

  auto stage = [&](const ushort* __restrict__ g, ushort* l, int r0, int k0){
    int c = wid << 1;
    const ushort* s0 = g + (size_t)(r0 + (c<<4) + (lane>>2))*K + k0 + ((lane&3)<<3);
    async_copy16(l + (c<<9), s0);
    async_copy16(l + ((c+1)<<9), s0 + (size_t)16*K);
  };

  int nk = K >> 5;
  stage(Ah, lAh, row0, 0); stage(Al, lAl, row0, 0);
  stage(Bh, lBh, col0, 0); stage(Bl, lBl, col0, 0);
  int wm = (wid >> 1) << 6, wn = (wid & 1) << 6;
  int kg = (lane >> 4) << 3;
  int ar = lane & 15;

  for (int kt = 0; kt < nk; ++kt){
    __syncthreads();
    bf16x8 afh[4], afl[4], bfh[4], bfl[4];
    #pragma unroll
    for (int mi = 0; mi < 4; ++mi){
      afh[mi] = *(const bf16x8*)&lAh[(wm + mi*16 + ar)*32 + kg];
      afl[mi] = *(const bf16x8*)&lAl[(wm + mi*16 + ar)*32 + kg];
    }
    #pragma unroll
    for (int ni = 0; ni < 4; ++ni){
      bfh[ni] = *(const bf16x8*)&lBh[(wn + ni*16 + ar)*32 + kg];
      bfl[ni] = *(const bf16x8*)&lBl[(wn + ni*16 + ar)*32 + kg];
    }
    #pragma unroll
    for (int mi = 0; mi < 4; ++mi)
      #pragma unroll
      for (int ni = 0; ni < 4; ++ni){
        acc[mi][ni] = __builtin_amdgcn_mfma_f32_16x16x32_bf16(afh[mi], bfh[ni], acc[mi][ni], 0, 0, 0);
        acc[mi][ni] = __builtin_amdgcn_mfma_f32_16x16x32_bf16(afh[mi], bfl[ni], acc[mi][ni], 0, 0, 0);
        acc[mi][ni] = __builtin_amdgcn_mfma_f32_16x16x32_bf16(afl[mi], bfh[ni], acc[mi][ni], 0, 0, 0);
      }
    if (kt + 1 < nk){
      __syncthreads();
      stage(Ah, lAh, row0, (kt+1) << 5); stage(Al, lAl, row0, (kt+1) << 5);
      stage(Bh, lBh, col0, (kt+1) << 5); stage(Bl, lBl, col0, (kt+1) << 5);
    }
  }

  int rr = (lane >> 4) << 2;
  #pragma unroll
  for (int mi = 0; mi < 4; ++mi)
    #pragma unroll
    for (int ni = 0; ni < 4; ++ni){
      int r  = row0 + wm + mi*16 + rr;
      int cc = col0 + wn + ni*16 + ar;
      #pragma unroll
      for (int q = 0; q < 4; ++q)
        C[(size_t)(r + q) * N + cc] = acc[mi][ni][q];
    }
}

// ---------------- persistent recurrence (r10, unchanged): tagged dataflow ----------------
__global__ __launch_bounds__(512) void ran_all(
    unsigned* __restrict__ pub, const float* __restrict__ hiddenf,
    const ushort* __restrict__ wh, const ushort* __restrict__ wl,
    const float* __restrict__ b_i, const float* __restrict__ b_f,
    const float* __restrict__ ixfx, const float* __restrict__ x_all,
    float* __restrict__ hid_final)
{
  __shared__ ushort lWh[32*WSTRIDE];
  __shared__ ushort lWl[32*WSTRIDE];
  __shared__ f32x4 part[4][2][2][64];   // [kq][mh][gate][lane]
  __shared__ float gsm[2*32*17];
  __shared__ float cfl[32][17];

  int tid = threadIdx.x, lane = tid & 63, wid = tid >> 6;
  int kq = wid & 3, mh = wid >> 2;           // MFMA roles
  int rgate = wid & 1, rmh = (wid >> 1) & 1; // reduce roles (wid<4)
  int bid = blockIdx.x;
  int nb = bid << 4;
  int ar = lane & 15, kg = (lane >> 4) << 3;
  int um = tid >> 4, uk = tid & 15;

  #pragma unroll
  for (int u = 0; u < 8; ++u){
    int unit = u*512 + tid;
    int r = unit >> 7, off = (unit & 127) << 3;
    int g = r >> 4, c = r & 15;
    size_t gsrc = (size_t)((g<<10) + nb + c) * H_DIM + off;
    *(bf16x8*)&lWh[r*WSTRIDE + off] = *(const bf16x8*)&wh[gsrc];
    *(bf16x8*)&lWl[r*WSTRIDE + off] = *(const bf16x8*)&wl[gsrc];
  }
  cfl[um][uk] = hiddenf[(um<<10) + nb + uk];
  float bb = (rgate ? b_f : b_i)[nb + ar];
  const ushort* b0h = &lWh[(     ar)*WSTRIDE + (kq<<8) + kg];
  const ushort* b0l = &lWl[(     ar)*WSTRIDE + (kq<<8) + kg];
  const ushort* b1h = &lWh[(16 + ar)*WSTRIDE + (kq<<8) + kg];
  const ushort* b1l = &lWl[(16 + ar)*WSTRIDE + (kq<<8) + kg];
  int abase = (kq<<13) + ((kg>>4)<<9) + (((mh<<4) + ar)<<4) + (kg & 8);
  __syncthreads();

  for (int t = 0; t < T_DIM; ++t){
    float xq1 = x_all[((size_t)t<<15) + (um<<10) + nb + uk];
    float pix[4];
    if (wid < 4){
      const float* ix_t = ixfx + ((size_t)t<<16);
      #pragma unroll
      for (int q = 0; q < 4; ++q){
        int m = (rmh<<4) + ((lane>>4)<<2) + q;
        pix[q] = ix_t[m*2048 + (rgate<<10) + nb + ar];
      }
    }

    const unsigned* ps = pub + ((size_t)t << 15) + abase;
    unsigned expt = (unsigned)(t + 1) << 16;
    u32x4 w0[8], w1[8];
    int tries = 0;
    while (1){
      #pragma unroll
      for (int f = 0; f < 8; ++f){
        const unsigned* p = ps + (f << 10);
        asm volatile("global_load_dwordx4 %0, %2, off sc0 sc1\n\t"
                     "global_load_dwordx4 %1, %2, off offset:16 sc0 sc1"
                     : "=&v"(w0[f]), "=&v"(w1[f]) : "v"(p));
      }
      asm volatile("s_waitcnt vmcnt(0)" ::: "memory");
      __builtin_amdgcn_sched_barrier(0);
      unsigned bad = 0;
      #pragma unroll
      for (int f = 0; f < 8; ++f){
        bad |= (w0[f][0]^expt)|(w0[f][1]^expt)|(w0[f][2]^expt)|(w0[f][3]^expt)
             | (w1[f][0]^expt)|(w1[f][1]^expt)|(w1[f][2]^expt)|(w1[f][3]^expt);
      }
      if (__ballot((bad & 0xFFFF0000u) != 0) == 0ull) break;
      if (++tries > (1<<15)) break;   // bounded: fail fast, not hang
    }

    f32x4 g0h = {}, g0l = {}, g1h = {}, g1l = {};
    #pragma unroll
    for (int f = 0; f < 8; ++f){
      union { unsigned u[4]; bf16x8 v; } cv;
      cv.u[0] = (w0[f][0] & 0xFFFFu) | (w0[f][1] << 16);
      cv.u[1] = (w0[f][2] & 0xFFFFu) | (w0[f][3] << 16);
      cv.u[2] = (w1[f][0] & 0xFFFFu) | (w1[f][1] << 16);
      cv.u[3] = (w1[f][2] & 0xFFFFu) | (w1[f][3] << 16);
      int ob = f << 5;
      bf16x8 v0h = *(const bf16x8*)&b0h[ob];
      bf16x8 v0l = *(const bf16x8*)&b0l[ob];
      bf16x8 v1h = *(const bf16x8*)&b1h[ob];
      bf16x8 v1l = *(const bf16x8*)&b1l[ob];
      g0h = __builtin_amdgcn_mfma_f32_16x16x32_bf16(cv.v, v0h, g0h, 0, 0, 0);
      g0l = __builtin_amdgcn_mfma_f32_16x16x32_bf16(cv.v, v0l, g0l, 0, 0, 0);
      g1h = __builtin_amdgcn_mfma_f32_16x16x32_bf16(cv.v, v1h, g1h, 0, 0, 0);
      g1l = __builtin_amdgcn_mfma_f32_16x16x32_bf16(cv.v, v1l, g1l, 0, 0, 0);
    }
    part[kq][mh][0][lane] = g0h + g0l;
    part[kq][mh][1][lane] = g1h + g1l;
    __syncthreads();

    if (wid < 4){
      f32x4 sum = part[0][rmh][rgate][lane] + part[1][rmh][rgate][lane]
                + part[2][rmh][rgate][lane] + part[3][rmh][rgate][lane];
      #pragma unroll
      for (int q = 0; q < 4; ++q){
        int m = (rmh<<4) + ((lane>>4)<<2) + q;
        float pre = sum[q] + bb + pix[q];
        gsm[((rgate<<5) + m)*17 + ar] = 1.f / (1.f + expf(-pre));
      }
    }
    __syncthreads();

    {
      float iv = gsm[um*17 + uk];
      float fv = gsm[(32+um)*17 + uk];
      float cv2 = cfl[um][uk];
      float cn = iv * xq1 + fv * cv2;
      cfl[um][uk] = cn;
      unsigned word = ((unsigned)(t + 2) << 16) | (unsigned)f2bf(cn);
      __hip_atomic_store(&pub[((size_t)(t+1) << 15) + (bid << 9) + tid], word,
                         __ATOMIC_RELAXED, __HIP_MEMORY_SCOPE_AGENT);
      if (t == T_DIM-1) hid_final[(um<<10) + nb + uk] = cn;
    }
    __syncthreads();
  }
}

// init: write tagged c_init into pub slot 0 (tag = 1)
__global__ void init_c_kernel(const float* __restrict__ hidden, unsigned* __restrict__ pub){
  int i = blockIdx.x * blockDim.x + threadIdx.x;   // 0..32767
  float v = hidden[i];
  int m = i >> 10, col = i & 1023;
  pub[((col>>4)<<9) + (m<<4) + (col&15)] = (1u << 16) | (unsigned)f2bf(v);
}

// untag: pub slots 1..128 -> cstate [t][chunk][m][k] bf16 (for gemm256)
__global__ void untag_kernel(const unsigned* __restrict__ pub, ushort* __restrict__ cst){
  int e = (blockIdx.x * blockDim.x + threadIdx.x) << 2;  // 4 elems/thread
  int s = e >> 15, w = e & 32767;
  const unsigned* p = pub + ((size_t)(s + 1) << 15) + w;
  ushort4 o = make_ushort4((ushort)p[0], (ushort)p[1], (ushort)p[2], (ushort)p[3]);
  *(ushort4*)&cst[e] = o;
}

// ---------------- lse reduce + subtract ----------------
__global__ __launch_bounds__(64) void lse_reduce(const float* __restrict__ pmax,
                                                 const float* __restrict__ psum,
                                                 float* __restrict__ lse, int ntn){
  int row = blockIdx.x, lane = threadIdx.x;
  float m = -1e30f, s = 0.f;
  for (int i = lane; i < ntn; i += 64){
    float mi = pmax[(size_t)row*ntn + i], si = psum[(size_t)row*ntn + i];
    float M = fmaxf(m, mi);
    s = s*expf(m - M) + si*expf(mi - M);
    m = M;
  }
  #pragma unroll
  for (int o = 32; o; o >>= 1){
    float m2 = __shfl_xor(m, o), s2 = __shfl_xor(s, o);
    float M = fmaxf(m, m2);
    s = s*expf(m - M) + s2*expf(m2 - M);
    m = M;
  }
  if (lane == 0) lse[row] = m + logf(s);
}

__global__ __launch_bounds__(256) void sub_kernel(float* __restrict__ logits,
                                                  const float* __restrict__ lse){
  size_t row = blockIdx.x;
  float l = lse[row];
  float4* p4 = (float4*)(logits + row * (size_t)V_DIM);
  for (int i = threadIdx.x; i < V_DIM/4; i += 256){
    float4 v = p4[i];
    v.x -= l; v.y -= l; v.z -= l; v.w -= l;
    p4[i] = v;
  }
}

// ---------------- launch ----------------
extern "C" void kernel_launch(void* const* d_in, const int* in_sizes, int n_in,
                              void* d_out, int out_size, void* d_ws, size_t ws_size,
                              hipStream_t stream)
{
  const float* input  = (const float*)d_in[0];
  const float* hidden = (const float*)d_in[1];
  const float* w_ic   = (const float*)d_in[2];
  const float* w_ix   = (const float*)d_in[3];
  const float* w_fc   = (const float*)d_in[4];
  const float* w_fx   = (const float*)d_in[5];
  const float* b_i    = (const float*)d_in[6];
  const float* b_f    = (const float*)d_in[7];
  const float* W_out  = (const float*)d_in[8];
  const float* b_out  = (const float*)d_in[9];
  float* out = (float*)d_out;

  char* ws = (char*)d_ws;
  ushort* wout_bf = (ushort*)(ws + 0);          // 0 .. 65,536,000
  ushort* in_hi   = (ushort*)(ws + 65536000);   // cast targets (dead after split-gemm)
  ushort* in_lo   = (ushort*)(ws + 73924608);
  ushort* wx_hi   = (ushort*)(ws + 82313216);   // dead after split-gemm
  ushort* wx_lo   = (ushort*)(ws + 86507520);
  ushort* wc_hi   = (ushort*)(ws + 90701824);   // dead after ran_all
  ushort* wc_lo   = (ushort*)(ws + 94896128);
  // overlays (regions dead at time of use):
  unsigned* pub   = (unsigned*)(ws + 65536000); // [129][32768] tagged c, 16,908,288 B
  ushort* cstate  = (ushort*)(ws + 82444288);   // [128][32768] bf16, 8,388,608 B (post-ran_all)
  float*  pmax    = (float*)(ws + 94896128);    // [4096][125] over wc_lo (dead post-ran_all)
  float*  psum    = (float*)(ws + 99090432);
  float*  lse     = (float*)(ws + 103186432);   // 16 KB
  float*  ixfx    = out;                        // [4096][2048] scratch in logits region

  cast_bf16_kernel <<<2048,256,0,stream>>>(W_out, wout_bf, V_DIM*H_DIM/4);
  cast_split_kernel<<<1024,256,0,stream>>>(input, in_hi, in_lo, MROWS*H_DIM/4);
  cast_split_kernel<<<256,256,0,stream>>>(w_ix, wx_hi,             wx_lo,             H_DIM*H_DIM/4);
  cast_split_kernel<<<256,256,0,stream>>>(w_fx, wx_hi+H_DIM*H_DIM, wx_lo+H_DIM*H_DIM, H_DIM*H_DIM/4);
  cast_split_kernel<<<256,256,0,stream>>>(w_ic, wc_hi,             wc_lo,             H_DIM*H_DIM/4);
  cast_split_kernel<<<256,256,0,stream>>>(w_fc, wc_hi+H_DIM*H_DIM, wc_lo+H_DIM*H_DIM, H_DIM*H_DIM/4);

  // ixfx = input @ [w_ix; w_fx]^T (split-bf16, fused) — before pub overlays in_hi
  gemm_bt_split<<<32*16,256,0,stream>>>(in_hi, in_lo, wx_hi, wx_lo, ixfx, 2048, H_DIM, 16);

  // clear tags (graph-replay safety), seed slot 0
  hipMemsetAsync(pub, 0, (size_t)129 * PUBSTEP * 4, stream);
  init_c_kernel<<<128,256,0,stream>>>(hidden, pub);

  ran_all<<<NBLK,512,0,stream>>>(pub, hidden, wc_hi, wc_lo, b_i, b_f,
                                 ixfx, input, out + (size_t)MROWS*V_DIM);

  // pub -> cstate (bf16), then 256^2-tile logits GEMM + fused LSE partials
  untag_kernel<<<4096,256,0,stream>>>(pub, cstate);
  gemm256<<<2000,512,0,stream>>>(cstate, wout_bf, out, b_out, pmax, psum);
  lse_reduce<<<MROWS,64,0,stream>>>(pmax, psum, lse, 125);
  sub_kernel<<<MROWS,256,0,stream>>>(out, lse);
}

// Round 12
// 1865.012 us; speedup vs baseline: 1.1001x; 1.0266x over previous
//
#include <hip/hip_runtime.h>

typedef __attribute__((ext_vector_type(4))) float f32x4;
typedef __attribute__((ext_vector_type(8))) short bf16x8;
typedef __attribute__((ext_vector_type(4))) unsigned u32x4;

#define T_DIM 128
#define B_DIM 32
#define H_DIM 1024
#define V_DIM 32000
#define MROWS 4096    // T*B
#define NBLK 64       // persistent recurrence blocks
#define PUBSTEP 32768 // dwords per slot in tagged pub buffer
#define WSTRIDE 1028  // LDS W row stride (ushorts): bank step 2 -> conflict-free
#define GBK 32        // gemm256 K-tile

__device__ __forceinline__ ushort f2bf(float f){
  union { float f; unsigned u; } x; x.f = f;
  unsigned u = x.u;
  unsigned r = (u + 0x7fffu + ((u >> 16) & 1u)) >> 16;
  return (ushort)r;
}
__device__ __forceinline__ float bf2f(ushort h){
  union { unsigned u; float f; } x; x.u = ((unsigned)h) << 16;
  return x.f;
}

__device__ __forceinline__ void async_copy16(void* lds, const void* g){
  __builtin_amdgcn_global_load_lds((const __attribute__((address_space(1))) void*)g,
                                   (__attribute__((address_space(3))) void*)lds, 16, 0, 0);
}

// ---------------- casts ----------------
__global__ void cast_bf16_kernel(const float* __restrict__ s, ushort* __restrict__ d, int n4){
  int stride = gridDim.x * blockDim.x;
  for (int i = blockIdx.x*blockDim.x + threadIdx.x; i < n4; i += stride){
    float4 v = ((const float4*)s)[i];
    ushort4 o = make_ushort4(f2bf(v.x), f2bf(v.y), f2bf(v.z), f2bf(v.w));
    ((ushort4*)d)[i] = o;
  }
}

__global__ void cast_split_kernel(const float* __restrict__ s, ushort* __restrict__ dh,
                                  ushort* __restrict__ dl, int n4){
  int stride = gridDim.x * blockDim.x;
  for (int i = blockIdx.x*blockDim.x + threadIdx.x; i < n4; i += stride){
    float4 v = ((const float4*)s)[i];
    ushort4 h = make_ushort4(f2bf(v.x), f2bf(v.y), f2bf(v.z), f2bf(v.w));
    ushort4 l = make_ushort4(f2bf(v.x - bf2f(h.x)), f2bf(v.y - bf2f(h.y)),
                             f2bf(v.z - bf2f(h.z)), f2bf(v.w - bf2f(h.w)));
    ((ushort4*)dh)[i] = h;
    ((ushort4*)dl)[i] = l;
  }
}

// ---------------- plain m97-style bf16 GEMM (for ixfx) ----------------
__global__ __launch_bounds__(256) void gemm_bt_plain(
    const ushort* __restrict__ A, const ushort* __restrict__ B,
    float* __restrict__ C, int N, int K, int NTN)
{
  __shared__ ushort lA[128*32];
  __shared__ ushort lB[128*32];
  int tid = threadIdx.x;
  int lane = tid & 63, wid = tid >> 6;
  int tm = blockIdx.x / NTN, tn = blockIdx.x % NTN;
  int row0 = tm << 7, col0 = tn << 7;

  f32x4 acc[4][4] = {};

  auto stage = [&](const ushort* __restrict__ g, ushort* l, int r0, int k0){
    int c = wid << 1;
    const ushort* s0 = g + (size_t)(r0 + (c<<4) + (lane>>2))*K + k0 + ((lane&3)<<3);
    async_copy16(l + (c<<9), s0);
    async_copy16(l + ((c+1)<<9), s0 + (size_t)16*K);
  };

  int nk = K >> 5;
  stage(A, lA, row0, 0);
  stage(B, lB, col0, 0);
  int wm = (wid >> 1) << 6, wn = (wid & 1) << 6;
  int kg = (lane >> 4) << 3;
  int ar = lane & 15;

  for (int kt = 0; kt < nk; ++kt){
    __syncthreads();
    bf16x8 af[4], bfr[4];
    #pragma unroll
    for (int mi = 0; mi < 4; ++mi) af[mi]  = *(const bf16x8*)&lA[(wm + mi*16 + ar)*32 + kg];
    #pragma unroll
    for (int ni = 0; ni < 4; ++ni) bfr[ni] = *(const bf16x8*)&lB[(wn + ni*16 + ar)*32 + kg];
    #pragma unroll
    for (int mi = 0; mi < 4; ++mi)
      #pragma unroll
      for (int ni = 0; ni < 4; ++ni)
        acc[mi][ni] = __builtin_amdgcn_mfma_f32_16x16x32_bf16(af[mi], bfr[ni], acc[mi][ni], 0, 0, 0);
    if (kt + 1 < nk){
      __syncthreads();
      stage(A, lA, row0, (kt+1) << 5);
      stage(B, lB, col0, (kt+1) << 5);
    }
  }

  int rr = (lane >> 4) << 2;
  #pragma unroll
  for (int mi = 0; mi < 4; ++mi)
    #pragma unroll
    for (int ni = 0; ni < 4; ++ni){
      int r  = row0 + wm + mi*16 + rr;
      int cc = col0 + wn + ni*16 + ar;
      #pragma unroll
      for (int q = 0; q < 4; ++q)
        C[(size_t)(r + q) * N + cc] = acc[mi][ni][q];
    }
}

// ---------------- Vproj: 256x256-tile, BK=32, 4-deep counted-vmcnt pipeline ----------------
// C[4096][32000] = A(cstate chunked)[4096][1024] * B[32000][1024]^T + bias, fused LSE partials.
// A chunked: row r -> t=r>>5, m=r&31; elem addr = t*32768 + (k>>4)*512 + m*16 + (k&15).
// 32 K-tiles in 4 LDS slots; stage tile t+2 at tile t; vmcnt(8) drains tile t's 4 oldest
// loads (FIFO). One barrier per tile (slot WAR barrier-separated by 2 tiles). Granule
// swizzle phys = conc ^ ((row>>1)&3): 16-row frag reads spread over 8 bank-quads (2-way, free).
__global__ __launch_bounds__(512) void gemm256(
    const ushort* __restrict__ A, const ushort* __restrict__ B,
    float* __restrict__ C, const float* __restrict__ bias,
    float* __restrict__ pmax, float* __restrict__ psum)
{
  __shared__ ushort lA[4][256*GBK];
  __shared__ ushort lB[4][256*GBK];
  __shared__ float redm[2][4][128], reds[2][4][128];

  const int K = 1024, N = V_DIM, NTN = 125, NT = 32;
  int tid = threadIdx.x, lane = tid & 63, wid = tid >> 6;
  int wm = wid >> 2, wn = wid & 3;
  int bid = blockIdx.x;
  int xcd = bid & 7, id = bid >> 3;       // 2000 blocks: 250 per XCD
  int tm = (xcd << 1) | (id & 1);         // 2 M-bands per XCD (A band L2-resident)
  int tn = id >> 1;                       // 125 N-tiles
  int row0 = tm << 8, col0 = tn << 8;
  int ar = lane & 15, kg = (lane >> 4) << 3;

  auto STAGE = [&](int slot, int kt){
    int k0 = kt << 5;
    #pragma unroll
    for (int j = 0; j < 2; ++j){
      int u = j*512 + tid;                 // A 16B unit: 1024 units
      int r = u >> 2, p = u & 3;           // row, physical granule
      int g = p ^ ((r >> 1) & 3);          // conceptual granule
      int rA = row0 + r, k = k0 + (g << 3);
      const ushort* sA = A + ((size_t)(rA>>5)<<15) + ((size_t)(k>>4)<<9) + ((rA&31)<<4) + (k&15);
      async_copy16(&lA[slot][u<<3], sA);
    }
    #pragma unroll
    for (int j = 0; j < 2; ++j){
      int u = j*512 + tid;
      int r = u >> 2, p = u & 3;
      int g = p ^ ((r >> 1) & 3);
      const ushort* sB = B + (size_t)(col0 + r)*K + k0 + (g << 3);
      async_copy16(&lB[slot][u<<3], sB);
    }
  };

  f32x4 acc[8][4] = {};

  STAGE(0, 0);
  STAGE(1, 1);
  int gk = kg >> 3;                        // conceptual granule of this lane group
  for (int t = 0; t < NT; ++t){
    if (t + 2 < NT) STAGE((t+2) & 3, t+2);
    if (t + 2 < NT)      asm volatile("s_waitcnt vmcnt(8)" ::: "memory");
    else if (t + 1 < NT) asm volatile("s_waitcnt vmcnt(4)" ::: "memory");
    else                 asm volatile("s_waitcnt vmcnt(0)" ::: "memory");
    __builtin_amdgcn_s_barrier();
    __builtin_amdgcn_sched_barrier(0);
    const ushort* bufA = lA[t & 3];
    const ushort* bufB = lB[t & 3];
    bf16x8 a[8], b[4];
    #pragma unroll
    for (int fr = 0; fr < 8; ++fr){
      int row = wm*128 + fr*16 + ar;
      int phys = gk ^ ((row >> 1) & 3);
      a[fr] = *(const bf16x8*)&bufA[row*GBK + (phys << 3)];
    }
    #pragma unroll
    for (int fc = 0; fc < 4; ++fc){
      int row = wn*64 + fc*16 + ar;
      int phys = gk ^ ((row >> 1) & 3);
      b[fc] = *(const bf16x8*)&bufB[row*GBK + (phys << 3)];
    }
    __builtin_amdgcn_s_setprio(1);
    #pragma unroll
    for (int fr = 0; fr < 8; ++fr)
      #pragma unroll
      for (int fc = 0; fc < 4; ++fc)
        acc[fr][fc] = __builtin_amdgcn_mfma_f32_16x16x32_bf16(a[fr], b[fc], acc[fr][fc], 0, 0, 0);
    __builtin_amdgcn_s_setprio(0);
    __builtin_amdgcn_sched_barrier(0);
  }

  // epilogue: bias + C-write + per-(row, tile) LSE partials
  float bb4[4];
  #pragma unroll
  for (int fc = 0; fc < 4; ++fc) bb4[fc] = bias[col0 + wn*64 + fc*16 + ar];
  #pragma unroll
  for (int fr = 0; fr < 8; ++fr){
    #pragma unroll
    for (int q = 0; q < 4; ++q){
      int rl = fr*16 + (lane>>4)*4 + q;
      int r = row0 + wm*128 + rl;
      float vals[4];
      #pragma unroll
      for (int fc = 0; fc < 4; ++fc){
        vals[fc] = acc[fr][fc][q] + bb4[fc];
        C[(size_t)r * N + col0 + wn*64 + fc*16 + ar] = vals[fc];
      }
      float m = fmaxf(fmaxf(vals[0], vals[1]), fmaxf(vals[2], vals[3]));
      #pragma unroll
      for (int o = 1; o < 16; o <<= 1) m = fmaxf(m, __shfl_xor(m, o));
      float s = expf(vals[0]-m) + expf(vals[1]-m) + expf(vals[2]-m) + expf(vals[3]-m);
      #pragma unroll
      for (int o = 1; o < 16; o <<= 1) s += __shfl_xor(s, o);
      if (ar == 0){ redm[wm][wn][rl] = m; reds[wm][wn][rl] = s; }
    }
  }
  __syncthreads();
  if (tid < 256){
    int wm2 = tid >> 7, rl = tid & 127;
    float m0 = redm[wm2][0][rl], m1 = redm[wm2][1][rl];
    float m2 = redm[wm2][2][rl], m3 = redm[wm2][3][rl];
    float M = fmaxf(fmaxf(m0, m1), fmaxf(m2, m3));
    float S = reds[wm2][0][rl]*expf(m0-M) + reds[wm2][1][rl]*expf(m1-M)
            + reds[wm2][2][rl]*expf(m2-M) + reds[wm2][3][rl]*expf(m3-M);
    int r = row0 + wm2*128 + rl;
    pmax[(size_t)r*NTN + tn] = M;
    psum[(size_t)r*NTN + tn] = S;
  }
}

// ---------------- persistent recurrence (r10, unchanged): tagged dataflow ----------------
__global__ __launch_bounds__(512) void ran_all(
    unsigned* __restrict__ pub, const float* __restrict__ hiddenf,
    const ushort* __restrict__ wh, const ushort* __restrict__ wl,
    const float* __restrict__ b_i, const float* __restrict__ b_f,
    const float* __restrict__ ixfx, const float* __restrict__ x_all,
    float* __restrict__ hid_final)
{
  __shared__ ushort lWh[32*WSTRIDE];
  __shared__ ushort lWl[32*WSTRIDE];
  __shared__ f32x4 part[4][2][2][64];   // [kq][mh][gate][lane]
  __shared__ float gsm[2*32*17];
  __shared__ float cfl[32][17];

  int tid = threadIdx.x, lane = tid & 63, wid = tid >> 6;
  int kq = wid & 3, mh = wid >> 2;           // MFMA roles
  int rgate = wid & 1, rmh = (wid >> 1) & 1; // reduce roles (wid<4)
  int bid = blockIdx.x;
  int nb = bid << 4;
  int ar = lane & 15, kg = (lane >> 4) << 3;
  int um = tid >> 4, uk = tid & 15;

  #pragma unroll
  for (int u = 0; u < 8; ++u){
    int unit = u*512 + tid;
    int r = unit >> 7, off = (unit & 127) << 3;
    int g = r >> 4, c = r & 15;
    size_t gsrc = (size_t)((g<<10) + nb + c) * H_DIM + off;
    *(bf16x8*)&lWh[r*WSTRIDE + off] = *(const bf16x8*)&wh[gsrc];
    *(bf16x8*)&lWl[r*WSTRIDE + off] = *(const bf16x8*)&wl[gsrc];
  }
  cfl[um][uk] = hiddenf[(um<<10) + nb + uk];
  float bb = (rgate ? b_f : b_i)[nb + ar];
  const ushort* b0h = &lWh[(     ar)*WSTRIDE + (kq<<8) + kg];
  const ushort* b0l = &lWl[(     ar)*WSTRIDE + (kq<<8) + kg];
  const ushort* b1h = &lWh[(16 + ar)*WSTRIDE + (kq<<8) + kg];
  const ushort* b1l = &lWl[(16 + ar)*WSTRIDE + (kq<<8) + kg];
  int abase = (kq<<13) + ((kg>>4)<<9) + (((mh<<4) + ar)<<4) + (kg & 8);
  __syncthreads();

  for (int t = 0; t < T_DIM; ++t){
    float xq1 = x_all[((size_t)t<<15) + (um<<10) + nb + uk];
    float pix[4];
    if (wid < 4){
      const float* ix_t = ixfx + ((size_t)t<<16);
      #pragma unroll
      for (int q = 0; q < 4; ++q){
        int m = (rmh<<4) + ((lane>>4)<<2) + q;
        pix[q] = ix_t[m*2048 + (rgate<<10) + nb + ar];
      }
    }

    const unsigned* ps = pub + ((size_t)t << 15) + abase;
    unsigned expt = (unsigned)(t + 1) << 16;
    u32x4 w0[8], w1[8];
    int tries = 0;
    while (1){
      #pragma unroll
      for (int f = 0; f < 8; ++f){
        const unsigned* p = ps + (f << 10);
        asm volatile("global_load_dwordx4 %0, %2, off sc0 sc1\n\t"
                     "global_load_dwordx4 %1, %2, off offset:16 sc0 sc1"
                     : "=&v"(w0[f]), "=&v"(w1[f]) : "v"(p));
      }
      asm volatile("s_waitcnt vmcnt(0)" ::: "memory");
      __builtin_amdgcn_sched_barrier(0);
      unsigned bad = 0;
      #pragma unroll
      for (int f = 0; f < 8; ++f){
        bad |= (w0[f][0]^expt)|(w0[f][1]^expt)|(w0[f][2]^expt)|(w0[f][3]^expt)
             | (w1[f][0]^expt)|(w1[f][1]^expt)|(w1[f][2]^expt)|(w1[f][3]^expt);
      }
      if (__ballot((bad & 0xFFFF0000u) != 0) == 0ull) break;
      if (++tries > (1<<15)) break;   // bounded: fail fast, not hang
    }

    f32x4 g0h = {}, g0l = {}, g1h = {}, g1l = {};
    #pragma unroll
    for (int f = 0; f < 8; ++f){
      union { unsigned u[4]; bf16x8 v; } cv;
      cv.u[0] = (w0[f][0] & 0xFFFFu) | (w0[f][1] << 16);
      cv.u[1] = (w0[f][2] & 0xFFFFu) | (w0[f][3] << 16);
      cv.u[2] = (w1[f][0] & 0xFFFFu) | (w1[f][1] << 16);
      cv.u[3] = (w1[f][2] & 0xFFFFu) | (w1[f][3] << 16);
      int ob = f << 5;
      bf16x8 v0h = *(const bf16x8*)&b0h[ob];
      bf16x8 v0l = *(const bf16x8*)&b0l[ob];
      bf16x8 v1h = *(const bf16x8*)&b1h[ob];
      bf16x8 v1l = *(const bf16x8*)&b1l[ob];
      g0h = __builtin_amdgcn_mfma_f32_16x16x32_bf16(cv.v, v0h, g0h, 0, 0, 0);
      g0l = __builtin_amdgcn_mfma_f32_16x16x32_bf16(cv.v, v0l, g0l, 0, 0, 0);
      g1h = __builtin_amdgcn_mfma_f32_16x16x32_bf16(cv.v, v1h, g1h, 0, 0, 0);
      g1l = __builtin_amdgcn_mfma_f32_16x16x32_bf16(cv.v, v1l, g1l, 0, 0, 0);
    }
    part[kq][mh][0][lane] = g0h + g0l;
    part[kq][mh][1][lane] = g1h + g1l;
    __syncthreads();

    if (wid < 4){
      f32x4 sum = part[0][rmh][rgate][lane] + part[1][rmh][rgate][lane]
                + part[2][rmh][rgate][lane] + part[3][rmh][rgate][lane];
      #pragma unroll
      for (int q = 0; q < 4; ++q){
        int m = (rmh<<4) + ((lane>>4)<<2) + q;
        float pre = sum[q] + bb + pix[q];
        gsm[((rgate<<5) + m)*17 + ar] = 1.f / (1.f + expf(-pre));
      }
    }
    __syncthreads();

    {
      float iv = gsm[um*17 + uk];
      float fv = gsm[(32+um)*17 + uk];
      float cv2 = cfl[um][uk];
      float cn = iv * xq1 + fv * cv2;
      cfl[um][uk] = cn;
      unsigned word = ((unsigned)(t + 2) << 16) | (unsigned)f2bf(cn);
      __hip_atomic_store(&pub[((size_t)(t+1) << 15) + (bid << 9) + tid], word,
                         __ATOMIC_RELAXED, __HIP_MEMORY_SCOPE_AGENT);
      if (t == T_DIM-1) hid_final[(um<<10) + nb + uk] = cn;
    }
    __syncthreads();
  }
}

// init: write tagged c_init into pub slot 0 (tag = 1)
__global__ void init_c_kernel(const float* __restrict__ hidden, unsigned* __restrict__ pub){
  int i = blockIdx.x * blockDim.x + threadIdx.x;   // 0..32767
  float v = hidden[i];
  int m = i >> 10, col = i & 1023;
  pub[((col>>4)<<9) + (m<<4) + (col&15)] = (1u << 16) | (unsigned)f2bf(v);
}

// untag: pub slots 1..128 -> cstate [t][chunk][m][k] bf16 (for gemm256)
__global__ void untag_kernel(const unsigned* __restrict__ pub, ushort* __restrict__ cst){
  int e = (blockIdx.x * blockDim.x + threadIdx.x) << 2;  // 4 elems/thread
  int s = e >> 15, w = e & 32767;
  const unsigned* p = pub + ((size_t)(s + 1) << 15) + w;
  ushort4 o = make_ushort4((ushort)p[0], (ushort)p[1], (ushort)p[2], (ushort)p[3]);
  *(ushort4*)&cst[e] = o;
}

// ---------------- fused lse + subtract: one block per row ----------------
__global__ __launch_bounds__(256) void subf_kernel(float* __restrict__ logits,
                                                   const float* __restrict__ pmax,
                                                   const float* __restrict__ psum){
  __shared__ float sl;
  size_t row = blockIdx.x;
  int tid = threadIdx.x;
  if (tid < 64){
    float m = -1e30f, s = 0.f;
    for (int i = tid; i < 125; i += 64){
      float mi = pmax[row*125 + i], si = psum[row*125 + i];
      float M = fmaxf(m, mi);
      s = s*expf(m - M) + si*expf(mi - M);
      m = M;
    }
    #pragma unroll
    for (int o = 32; o; o >>= 1){
      float m2 = __shfl_xor(m, o), s2 = __shfl_xor(s, o);
      float M = fmaxf(m, m2);
      s = s*expf(m - M) + s2*expf(m2 - M);
      m = M;
    }
    if (tid == 0) sl = m + logf(s);
  }
  __syncthreads();
  float l = sl;
  float4* p4 = (float4*)(logits + row * (size_t)V_DIM);
  for (int i = tid; i < V_DIM/4; i += 256){
    float4 v = p4[i];
    v.x -= l; v.y -= l; v.z -= l; v.w -= l;
    p4[i] = v;
  }
}

// ---------------- launch ----------------
extern "C" void kernel_launch(void* const* d_in, const int* in_sizes, int n_in,
                              void* d_out, int out_size, void* d_ws, size_t ws_size,
                              hipStream_t stream)
{
  const float* input  = (const float*)d_in[0];
  const float* hidden = (const float*)d_in[1];
  const float* w_ic   = (const float*)d_in[2];
  const float* w_ix   = (const float*)d_in[3];
  const float* w_fc   = (const float*)d_in[4];
  const float* w_fx   = (const float*)d_in[5];
  const float* b_i    = (const float*)d_in[6];
  const float* b_f    = (const float*)d_in[7];
  const float* W_out  = (const float*)d_in[8];
  const float* b_out  = (const float*)d_in[9];
  float* out = (float*)d_out;

  char* ws = (char*)d_ws;
  ushort* wout_bf = (ushort*)(ws + 0);          // 0 .. 65,536,000
  ushort* in_hi   = (ushort*)(ws + 65536000);   // 8,388,608 (dead after ixfx gemm)
  ushort* wx      = (ushort*)(ws + 73924608);   // [w_ix; w_fx] plain bf16, 4,194,304
  ushort* wc_hi   = (ushort*)(ws + 90701824);   // split W for recurrence
  ushort* wc_lo   = (ushort*)(ws + 94896128);
  // overlays (regions dead at time of use):
  unsigned* pub   = (unsigned*)(ws + 65536000); // [129][32768] tagged c, 16,908,288 B
  ushort* cstate  = (ushort*)(ws + 82444288);   // [128][32768] bf16 (post-ran_all)
  float*  pmax    = (float*)(ws + 94896128);    // [4096][125] over wc_lo (dead post-ran_all)
  float*  psum    = (float*)(ws + 99090432);
  float*  ixfx    = out;                        // [4096][2048] scratch in logits region

  cast_bf16_kernel<<<2048,256,0,stream>>>(W_out, wout_bf, V_DIM*H_DIM/4);
  cast_bf16_kernel<<<1024,256,0,stream>>>(input, in_hi, MROWS*H_DIM/4);
  cast_bf16_kernel<<<256,256,0,stream>>>(w_ix, wx,             H_DIM*H_DIM/4);
  cast_bf16_kernel<<<256,256,0,stream>>>(w_fx, wx+H_DIM*H_DIM, H_DIM*H_DIM/4);
  cast_split_kernel<<<256,256,0,stream>>>(w_ic, wc_hi,             wc_lo,             H_DIM*H_DIM/4);
  cast_split_kernel<<<256,256,0,stream>>>(w_fc, wc_hi+H_DIM*H_DIM, wc_lo+H_DIM*H_DIM, H_DIM*H_DIM/4);

  // ixfx = input @ [w_ix; w_fx]^T (plain bf16) — before pub overlays in_hi/wx
  gemm_bt_plain<<<32*16,256,0,stream>>>(in_hi, wx, ixfx, 2048, H_DIM, 16);

  // clear tags (graph-replay safety), seed slot 0
  hipMemsetAsync(pub, 0, (size_t)129 * PUBSTEP * 4, stream);
  init_c_kernel<<<128,256,0,stream>>>(hidden, pub);

  ran_all<<<NBLK,512,0,stream>>>(pub, hidden, wc_hi, wc_lo, b_i, b_f,
                                 ixfx, input, out + (size_t)MROWS*V_DIM);

  // pub -> cstate (bf16), then 256^2-tile 4-deep-pipelined logits GEMM + LSE partials
  untag_kernel<<<4096,256,0,stream>>>(pub, cstate);
  gemm256<<<2000,512,0,stream>>>(cstate, wout_bf, out, b_out, pmax, psum);
  subf_kernel<<<MROWS,256,0,stream>>>(out, pmax, psum);
}